// Round 6
// baseline (3182.845 us; speedup 1.0000x reference)
//
#include <hip/hip_runtime.h>
#include <math.h>

#define Bsz 512
#define Nn  24
#define Tt  25
// IN=8, L=64, H=256, OUT=128
// layer1: per-step K = 8(loc,locd) + 128(h1) -> padded 192; z-part hoisted to base1
// layer2: K=256; fc: K=128; init: K=256 from enc (fp32)

typedef _Float16 f16;
typedef _Float16 f16x8 __attribute__((ext_vector_type(8)));
typedef _Float16 f16x4 __attribute__((ext_vector_type(4)));
typedef float f32x4 __attribute__((ext_vector_type(4)));

// ---------------------------------------------------------------------------
// MFMA fp16 GEMM, per-node block-diagonal, W-as-A orientation:
//   Y[b,n,o] = sum_k Act[b,n,k] * W[n,o,k] + bias[n,o] (+ base16[b,n,o])
// Register-prefetch pipelined K-loop (verified R4): loads for tile k+1 issue
// before the MFMA block of tile k.
// ---------------------------------------------------------------------------
template <int FM, int FN>
__global__ __launch_bounds__(256) void gemm_mfma(
    const f16* __restrict__ Act, const float* __restrict__ Act32, int Ka,
    const f16* __restrict__ W, size_t wstride,
    const float* __restrict__ bias, int bstride,
    const f16* __restrict__ base16,
    f16* __restrict__ Y, int O)
{
    const int BM = FM * 32, BN = FN * 32;
    const int n  = blockIdx.z;
    const int o0 = blockIdx.x * BM;
    const int b0 = blockIdx.y * BN;
    const int tid  = threadIdx.x;
    const int wave = tid >> 6, lane = tid & 63;
    const int wm = (wave >> 1) * FM * 16;   // o offset of wave
    const int wn = (wave & 1) * FN * 16;    // b offset of wave
    const int m16 = lane & 15, quad = lane >> 4;

    __shared__ __attribute__((aligned(16))) f16 sW[BM][72];  // o-rows, k-cols (+pad)
    __shared__ __attribute__((aligned(16))) f16 sB[BN][72];  // b-rows, k-cols

    const f16* Wn = W + (size_t)n * wstride;
    f32x4 acc[FM][FN] = {};

    const int r  = tid >> 3;        // staging row 0..31
    const int cc = (tid & 7) * 8;   // staging col (halfs)
    const int nk = Ka >> 6;         // 64-wide k tiles

    f16x8 rW[FM], rB[FN];
    float rBf[FN][8];

    // ---- prefetch k-tile 0 into registers ----
#pragma unroll
    for (int i = 0; i < FM; i++)
        rW[i] = *(const f16x8*)&Wn[(size_t)(o0 + r + 32 * i) * Ka + cc];
    if (Act) {
#pragma unroll
        for (int j = 0; j < FN; j++)
            rB[j] = *(const f16x8*)&Act[((size_t)(b0 + r + 32 * j) * Nn + n) * Ka + cc];
    } else {
#pragma unroll
        for (int j = 0; j < FN; j++) {
            const float* src = &Act32[((size_t)(b0 + r + 32 * j) * Nn + n) * Ka + cc];
#pragma unroll
            for (int u = 0; u < 8; u++) rBf[j][u] = src[u];
        }
    }

    for (int it = 0; it < nk; it++) {
        // ---- commit prefetched tile to LDS ----
#pragma unroll
        for (int i = 0; i < FM; i++)
            *(f16x8*)&sW[r + 32 * i][cc] = rW[i];
        if (Act) {
#pragma unroll
            for (int j = 0; j < FN; j++)
                *(f16x8*)&sB[r + 32 * j][cc] = rB[j];
        } else {
#pragma unroll
            for (int j = 0; j < FN; j++) {
                f16x8 v;
#pragma unroll
                for (int u = 0; u < 8; u++) v[u] = (f16)rBf[j][u];
                *(f16x8*)&sB[r + 32 * j][cc] = v;
            }
        }
        __syncthreads();

        // ---- issue next tile's global loads (latency hides under MFMA) ----
        if (it + 1 < nk) {
            const int k0n = (it + 1) << 6;
#pragma unroll
            for (int i = 0; i < FM; i++)
                rW[i] = *(const f16x8*)&Wn[(size_t)(o0 + r + 32 * i) * Ka + k0n + cc];
            if (Act) {
#pragma unroll
                for (int j = 0; j < FN; j++)
                    rB[j] = *(const f16x8*)&Act[((size_t)(b0 + r + 32 * j) * Nn + n) * Ka + k0n + cc];
            } else {
#pragma unroll
                for (int j = 0; j < FN; j++) {
                    const float* src = &Act32[((size_t)(b0 + r + 32 * j) * Nn + n) * Ka + k0n + cc];
#pragma unroll
                    for (int u = 0; u < 8; u++) rBf[j][u] = src[u];
                }
            }
        }

        // ---- MFMA on the committed LDS tile ----
#pragma unroll
        for (int kk = 0; kk < 64; kk += 32) {
            f16x8 af[FM], bf[FN];
#pragma unroll
            for (int i = 0; i < FM; i++)
                af[i] = *(const f16x8*)&sW[wm + i * 16 + m16][kk + quad * 8];
#pragma unroll
            for (int j = 0; j < FN; j++)
                bf[j] = *(const f16x8*)&sB[wn + j * 16 + m16][kk + quad * 8];
#pragma unroll
            for (int i = 0; i < FM; i++)
#pragma unroll
                for (int j = 0; j < FN; j++)
                    acc[i][j] = __builtin_amdgcn_mfma_f32_16x16x32_f16(af[i], bf[j], acc[i][j], 0, 0, 0);
        }
        __syncthreads();
    }
    // epilogue: D[row=o][col=b]; per lane, regs = 4 consecutive o at quad*4
#pragma unroll
    for (int i = 0; i < FM; i++) {
        const int orow = o0 + wm + i * 16 + quad * 4;
        float4 bv = make_float4(0.f, 0.f, 0.f, 0.f);
        if (bias) bv = *(const float4*)&bias[(size_t)n * bstride + orow];
#pragma unroll
        for (int j = 0; j < FN; j++) {
            const int bcol = b0 + wn + j * 16 + m16;
            size_t yi = ((size_t)bcol * Nn + n) * (size_t)O + orow;
            float v0 = acc[i][j][0] + bv.x;
            float v1 = acc[i][j][1] + bv.y;
            float v2 = acc[i][j][2] + bv.z;
            float v3 = acc[i][j][3] + bv.w;
            if (base16) {
                f16x4 bb = *(const f16x4*)&base16[yi];
                v0 += (float)bb[0]; v1 += (float)bb[1];
                v2 += (float)bb[2]; v3 += (float)bb[3];
            }
            f16x4 o4; o4[0] = (f16)v0; o4[1] = (f16)v1; o4[2] = (f16)v2; o4[3] = (f16)v3;
            *(f16x4*)&Y[yi] = o4;
        }
    }
}

// ---------------------------------------------------------------------------
// Weight prep: Wz (24,512,64)=Wx0[:, :64, :]^T; Wt0 (24,512,192)=[Wx0[64:72]|Wh0|0]^T;
// Wt1 (24,512,256)=[Wx1|Wh1]^T
// ---------------------------------------------------------------------------
__global__ __launch_bounds__(256) void prep_w01(
    const float* __restrict__ Wx0, const float* __restrict__ Wh0,
    const float* __restrict__ Wx1, const float* __restrict__ Wh1,
    f16* __restrict__ Wz, f16* __restrict__ Wt0, f16* __restrict__ Wt1)
{
    size_t idx = (size_t)blockIdx.x * 256 + threadIdx.x;
    const size_t nz = (size_t)Nn * 512 * 64;       // 786432
    const size_t n0 = (size_t)Nn * 512 * 192;      // 2359296
    const size_t n1 = (size_t)Nn * 512 * 256;      // 3145728
    if (idx < nz) {
        int k = idx & 63; int o = (idx >> 6) & 511; int n = (int)(idx >> 15);
        Wz[idx] = (f16)Wx0[((size_t)n * 72 + k) * 512 + o];
    } else if (idx < nz + n0) {
        size_t i2 = idx - nz;
        int k = (int)(i2 % 192);
        size_t no = i2 / 192;
        int o = (int)(no & 511); int n = (int)(no >> 9);
        float v = 0.f;
        if (k < 8) v = Wx0[((size_t)n * 72 + 64 + k) * 512 + o];
        else if (k < 136) v = Wh0[((size_t)n * 128 + (k - 8)) * 512 + o];
        Wt0[i2] = (f16)v;
    } else if (idx < nz + n0 + n1) {
        size_t i3 = idx - nz - n0;
        int k = (int)(i3 & 255);
        size_t no = i3 >> 8;
        int o = (int)(no & 511); int n = (int)(no >> 9);
        float v = (k < 128) ? Wx1[((size_t)n * 128 + k) * 512 + o]
                            : Wh1[((size_t)n * 128 + (k - 128)) * 512 + o];
        Wt1[i3] = (f16)v;
    }
}

// Wtf (24,256,128): o<128 -> fcW^T, else fc2W^T
__global__ __launch_bounds__(256) void prep_wf(
    const float* __restrict__ fcW, const float* __restrict__ fc2W,
    f16* __restrict__ Wtf)
{
    size_t idx = (size_t)blockIdx.x * 256 + threadIdx.x;
    if (idx >= (size_t)Nn * 256 * 128) return;
    int k = (int)(idx & 127);
    size_t no = idx >> 7;
    int o = (int)(no & 255); int n = (int)(no >> 8);
    float v = (o < 128) ? fcW[((size_t)n * 128 + k) * 128 + o]
                        : fc2W[((size_t)n * 128 + k) * 128 + (o - 128)];
    Wtf[idx] = (f16)v;
}

// Wti (256,256) = [ih1W | ih2W]^T ; bi (256) ; bcat (24,256)
__global__ __launch_bounds__(256) void prep_wi(
    const float* __restrict__ ih1W, const float* __restrict__ ih2W,
    const float* __restrict__ ih1b, const float* __restrict__ ih2b,
    const float* __restrict__ fcb, const float* __restrict__ fc2b,
    f16* __restrict__ Wti, float* __restrict__ bi, float* __restrict__ bcat)
{
    int idx = blockIdx.x * 256 + threadIdx.x;   // 65536
    int k = idx & 255, o = idx >> 8;
    Wti[idx] = (f16)((o < 128) ? ih1W[(size_t)k * 128 + o] : ih2W[(size_t)k * 128 + (o - 128)]);
    if (idx < 256) bi[idx] = (idx < 128) ? ih1b[idx] : ih2b[idx - 128];
    if (idx < Nn * 256) {
        int n = idx >> 8, oo = idx & 255;
        bcat[idx] = (oo < 128) ? fcb[n * 128 + oo] : fc2b[n * 128 + (oo - 128)];
    }
}

// xi2[b,n,0:8)=x, [136:192)=0 ([8:136) = h1, filled by mix_init/mixlstm); ls=x[:4]
__global__ __launch_bounds__(256) void init_xi(
    const float* __restrict__ x, f16* __restrict__ xi2, float* __restrict__ ls)
{
    size_t idx = (size_t)blockIdx.x * 256 + threadIdx.x;
    const size_t total = (size_t)Bsz * Nn * 192;
    if (idx < total) {
        size_t bn = idx / 192;
        int k = (int)(idx - bn * 192);
        if (k < 8) xi2[idx] = (f16)x[bn * 8 + k];
        else if (k >= 136) xi2[idx] = (f16)0.f;
    }
    if (idx < (size_t)Bsz * Nn * 4) {
        size_t bn = idx >> 2;
        ls[idx] = x[bn * 8 + (idx & 3)];
    }
}

// ---------------------------------------------------------------------------
// Init mix: Yhc (B,N,256) f16 = [h-pre | c-pre]; h0 -> xi2[8:136), l2cat[0:128),
// l2cat[128:256); c0 -> c1, c2 (fp32).
// Register-accumulate over this thread's m values: o = tid&127 is constant per
// thread, so sY[n*256(+128)+o] is read ONCE per n (was 12x). Accumulation
// order per output unchanged (n ascending) -> bit-identical.
// ---------------------------------------------------------------------------
__global__ __launch_bounds__(256) void mix_init(
    const f16* __restrict__ Yhc, const float* __restrict__ G,
    f16* __restrict__ xi2, f16* __restrict__ l2cat,
    float* __restrict__ c1, float* __restrict__ c2)
{
    const int b = blockIdx.x;
    const int tid = threadIdx.x;
    __shared__ float sY[6144], sG[576];
    for (int i = tid; i < 576; i += 256) sG[i] = G[i];
    for (int v = tid; v < 768; v += 256) {
        int c8 = (v & 31) * 8, n = v >> 5;
        f16x8 t = *(const f16x8*)&Yhc[((size_t)b * Nn + n) * 256 + c8];
        float* d = &sY[n * 256 + c8];
#pragma unroll
        for (int u = 0; u < 8; u++) d[u] = (float)t[u];
    }
    __syncthreads();
    {
        const int o  = tid & 127;
        const int mg = tid >> 7;          // 0..1 ; m = mg + 2*k, k=0..11
        float ah[12], ac[12];
#pragma unroll
        for (int k = 0; k < 12; k++) { ah[k] = 0.f; ac[k] = 0.f; }
        for (int n = 0; n < 24; n++) {
            float yh = sY[n * 256 + o];
            float yc = sY[n * 256 + 128 + o];
#pragma unroll
            for (int k = 0; k < 12; k++) {
                float g = sG[(mg + 2 * k) * 24 + n];
                ah[k] += g * yh;
                ac[k] += g * yc;
            }
        }
#pragma unroll
        for (int k = 0; k < 12; k++) {
            int m = mg + 2 * k;
            size_t row = (size_t)b * Nn + m;
            f16 hf = (f16)ah[k];
            xi2[row * 192 + 8 + o] = hf;
            l2cat[row * 256 + o] = hf;
            l2cat[row * 256 + 128 + o] = hf;
            c1[row * 128 + o] = ac[k];
            c2[row * 128 + o] = ac[k];
        }
    }
}

// ---------------------------------------------------------------------------
// G-mix + LSTM pointwise. Ypre (B,N,512) f16 pre-mix gates. c fp32 in/out.
// h written f16 to dstA (raw) and dstB (raw or tanh). grid (B, 2 j-tiles).
// Register-accumulate: j = tid&63 constant per thread, so the 4 gate values
// sY[n*256+g*64+j] are read ONCE per n and reused across this thread's 6 m's
// (was re-read 6x). Per-output FP order unchanged -> bit-identical.
// ---------------------------------------------------------------------------
__global__ __launch_bounds__(256) void mixlstm(
    const f16* __restrict__ Ypre, const float* __restrict__ G,
    float* __restrict__ c,
    f16* __restrict__ dstA, int strideA,
    f16* __restrict__ dstB, int strideB, int tanhB)
{
    const int b = blockIdx.x;
    const int jt = blockIdx.y * 64;
    const int tid = threadIdx.x;
    __shared__ float sY[6144];   // n, gate, j(64)
    __shared__ float sG[576];
    for (int i = tid; i < 576; i += 256) sG[i] = G[i];
    for (int v = tid; v < 768; v += 256) {
        int j8 = (v & 7) * 8, g = (v >> 3) & 3, n = v >> 5;
        f16x8 t = *(const f16x8*)&Ypre[((size_t)b * Nn + n) * 512 + g * 128 + jt + j8];
        float* d = &sY[n * 256 + g * 64 + j8];
#pragma unroll
        for (int u = 0; u < 8; u++) d[u] = (float)t[u];
    }
    __syncthreads();
    {
        const int j  = tid & 63;
        const int mg = tid >> 6;          // 0..3 ; m = mg + 4*k, k=0..5
        float ai[6], af_[6], ag[6], ao[6];
#pragma unroll
        for (int k = 0; k < 6; k++) { ai[k] = 0.f; af_[k] = 0.f; ag[k] = 0.f; ao[k] = 0.f; }
        for (int n = 0; n < 24; n++) {
            const float* yr = &sY[n * 256 + j];
            float y0 = yr[0];
            float y1 = yr[64];
            float y2 = yr[128];
            float y3 = yr[192];
#pragma unroll
            for (int k = 0; k < 6; k++) {
                float g = sG[(mg + 4 * k) * 24 + n];
                ai[k] += g * y0;
                af_[k] += g * y1;
                ag[k] += g * y2;
                ao[k] += g * y3;
            }
        }
        const int col = jt + j;
#pragma unroll
        for (int k = 0; k < 6; k++) {
            int m = mg + 4 * k;
            size_t row = (size_t)b * Nn + m;
            float cv = c[row * 128 + col];
            float si = 1.f / (1.f + expf(-ai[k]));
            float sf = 1.f / (1.f + expf(-af_[k]));
            float so = 1.f / (1.f + expf(-ao[k]));
            float tg = tanhf(ag[k]);
            cv = sf * cv + si * tg;
            c[row * 128 + col] = cv;
            float h = so * tanhf(cv);
            dstA[row * strideA + col] = (f16)h;
            dstB[row * strideB + col] = (f16)(tanhB ? tanhf(h) : h);
        }
    }
}

// ---------------------------------------------------------------------------
// Final per-step: mix fc pre-acts + tanh, head matvecs, second mix, quat,
// outputs, update xi2[0:8) & loc_start. p (B,N,256) f16 = [fc1-pre | fc2-pre].
// Mix phase register-accumulates (o = tid&127 const per thread, sP read once
// per n instead of 12x). Matvec/quat phases unchanged (bit-identical).
// ---------------------------------------------------------------------------
__global__ __launch_bounds__(256) void finstep(
    const f16* __restrict__ p, const float* __restrict__ G,
    const float* __restrict__ locW, const float* __restrict__ locb,
    const float* __restrict__ lzW, const float* __restrict__ lzb,
    float* __restrict__ ls, f16* __restrict__ xi2,
    float* __restrict__ out, int t)
{
    const int b = blockIdx.x;
    const int tid = threadIdx.x;
    __shared__ float sP[6144], sY1[3072], sY2[3072];
    __shared__ float sG[576];
    __shared__ float sLp[24][3], sZp[24][4], sL3[24][3], sZ3[24][4];
    for (int i = tid; i < 576; i += 256) sG[i] = G[i];
    for (int v = tid; v < 768; v += 256) {
        int c8 = (v & 31) * 8, n = v >> 5;
        f16x8 tv = *(const f16x8*)&p[((size_t)b * Nn + n) * 256 + c8];
        float* d = &sP[n * 256 + c8];
#pragma unroll
        for (int u = 0; u < 8; u++) d[u] = (float)tv[u];
    }
    __syncthreads();
    {
        const int o  = tid & 127;
        const int mg = tid >> 7;          // 0..1 ; m = mg + 2*k, k=0..11
        float a1[12], a2[12];
#pragma unroll
        for (int k = 0; k < 12; k++) { a1[k] = 0.f; a2[k] = 0.f; }
        for (int n = 0; n < 24; n++) {
            float p1 = sP[n * 256 + o];
            float p2 = sP[n * 256 + 128 + o];
#pragma unroll
            for (int k = 0; k < 12; k++) {
                float g = sG[(mg + 2 * k) * 24 + n];
                a1[k] += g * p1;
                a2[k] += g * p2;
            }
        }
#pragma unroll
        for (int k = 0; k < 12; k++) {
            int m = mg + 2 * k;
            sY1[m * 128 + o] = tanhf(a1[k]);
            sY2[m * 128 + o] = tanhf(a2[k]);
        }
    }
    __syncthreads();
    if (tid < 72) {
        int m = tid / 3, j = tid - m * 3;
        float s = locb[j];
        for (int o = 0; o < 128; o++) s += sY1[m * 128 + o] * locW[o * 3 + j];
        sLp[m][j] = s;
    } else if (tid < 168) {
        int w2 = tid - 72; int m = w2 >> 2, j = w2 & 3;
        float s = lzb[j];
        for (int o = 0; o < 128; o++) s += sY2[m * 128 + o] * lzW[o * 4 + j];
        sZp[m][j] = s;
    }
    __syncthreads();
    if (tid < 72) {
        int m = tid / 3, j = tid - m * 3;
        float s = 0.f;
#pragma unroll
        for (int n = 0; n < 24; n++) s += sG[m * 24 + n] * sLp[n][j];
        sL3[m][j] = s;
    } else if (tid < 168) {
        int w2 = tid - 72; int m = w2 >> 2, j = w2 & 3;
        float s = 0.f;
#pragma unroll
        for (int n = 0; n < 24; n++) s += sG[m * 24 + n] * sZp[n][j];
        sZ3[m][j] = s;
    }
    __syncthreads();
    if (tid < 24) {
        int m = tid;
        float xx = sL3[m][0], xy = sL3[m][1], xz = sL3[m][2];
        float r = rsqrtf(1.f + xx * xx + xy * xy + xz * xz);
        float dw = r, dx = xx * r, dy = xy * r, dz = xz * r;
        size_t li = ((size_t)b * Nn + m) * 4;
        float qw = ls[li], qx = ls[li + 1], qy = ls[li + 2], qz = ls[li + 3];
        float lw = qw * dw - qx * dx - qy * dy - qz * dz;
        float lx = qw * dx + qx * dw + qy * dz - qz * dy;
        float ly = qw * dy - qx * dz + qy * dw + qz * dx;
        float lz = qw * dz + qx * dy - qy * dx + qz * dw;
        size_t oi = (((size_t)b * Tt + t) * Nn + m) * 4;
        out[oi + 0] = lw; out[oi + 1] = lx; out[oi + 2] = ly; out[oi + 3] = lz;
        size_t zi = (size_t)Bsz * Tt * Nn * 4 + oi;
        out[zi + 0] = sZ3[m][0]; out[zi + 1] = sZ3[m][1];
        out[zi + 2] = sZ3[m][2]; out[zi + 3] = sZ3[m][3];
        ls[li] = lw; ls[li + 1] = lx; ls[li + 2] = ly; ls[li + 3] = lz;
        size_t xb = ((size_t)b * Nn + m) * 192;
        xi2[xb + 0] = (f16)lw; xi2[xb + 1] = (f16)lx; xi2[xb + 2] = (f16)ly; xi2[xb + 3] = (f16)lz;
        xi2[xb + 4] = (f16)dw; xi2[xb + 5] = (f16)dx; xi2[xb + 6] = (f16)dy; xi2[xb + 7] = (f16)dz;
    }
}

extern "C" void kernel_launch(void* const* d_in, const int* in_sizes, int n_in,
                              void* d_out, int out_size, void* d_ws, size_t ws_size,
                              hipStream_t stream)
{
    const float* x    = (const float*)d_in[0];
    const float* enc  = (const float*)d_in[1];
    const float* z    = (const float*)d_in[2];
    const float* G    = (const float*)d_in[4];
    const float* Wx0  = (const float*)d_in[5];
    const float* Wh0  = (const float*)d_in[6];
    const float* b0i  = (const float*)d_in[7];
    const float* Wx1  = (const float*)d_in[8];
    const float* Wh1  = (const float*)d_in[9];
    const float* b1i  = (const float*)d_in[10];
    const float* fcW  = (const float*)d_in[11];
    const float* fcb  = (const float*)d_in[12];
    const float* fc2W = (const float*)d_in[13];
    const float* fc2b = (const float*)d_in[14];
    const float* ih1W = (const float*)d_in[15];
    const float* ih1b = (const float*)d_in[16];
    const float* ih2W = (const float*)d_in[17];
    const float* ih2b = (const float*)d_in[18];
    const float* locW = (const float*)d_in[19];
    const float* locb = (const float*)d_in[20];
    const float* lzW  = (const float*)d_in[21];
    const float* lzb  = (const float*)d_in[22];
    float* out = (float*)d_out;

    const size_t BN = (size_t)Bsz * Nn;
    char* wp = (char*)d_ws;
    size_t off = 0;
    auto carve = [&](size_t bytes) -> char* {
        char* pc = wp + off;
        off += (bytes + 255) & ~(size_t)255;
        return pc;
    };
    f16*   Wz     = (f16*)carve((size_t)Nn * 512 * 64 * 2);
    f16*   Wt0    = (f16*)carve((size_t)Nn * 512 * 192 * 2);
    f16*   Wt1    = (f16*)carve((size_t)Nn * 512 * 256 * 2);
    f16*   Wtf    = (f16*)carve((size_t)Nn * 256 * 128 * 2);
    f16*   Wti    = (f16*)carve((size_t)256 * 256 * 2);
    float* bcat   = (float*)carve((size_t)Nn * 256 * 4);
    float* bi     = (float*)carve(256 * 4);
    f16*   base1  = (f16*)carve(BN * 512 * 2);
    f16*   xi2    = (f16*)carve(BN * 192 * 2);
    f16*   l2cat  = (f16*)carve(BN * 256 * 2);
    f16*   yib    = (f16*)carve(BN * 128 * 2);
    float* c1     = (float*)carve(BN * 128 * 4);
    float* c2     = (float*)carve(BN * 128 * 4);
    float* ls     = (float*)carve(BN * 4 * 4);
    f16*   yp     = (f16*)carve(BN * 512 * 2);
    f16*   pbuf   = (f16*)carve(BN * 256 * 2);

    // ---- one-time prep ----
    prep_w01<<<24576, 256, 0, stream>>>(Wx0, Wh0, Wx1, Wh1, Wz, Wt0, Wt1);
    prep_wf<<<3072, 256, 0, stream>>>(fcW, fc2W, Wtf);
    prep_wi<<<256, 256, 0, stream>>>(ih1W, ih2W, ih1b, ih2b, fcb, fc2b, Wti, bi, bcat);
    init_xi<<<9216, 256, 0, stream>>>(x, xi2, ls);

    // base1 = z . Wx0[:,:64,:] + b0    (constant over all T steps)
    gemm_mfma<2, 4><<<dim3(8, 4, 24), 256, 0, stream>>>(
        nullptr, z, 64, Wz, (size_t)512 * 64, b0i, 512, nullptr, base1, 512);
    // init states: [h0|c0] from enc
    gemm_mfma<2, 4><<<dim3(4, 4, 24), 256, 0, stream>>>(
        nullptr, enc, 256, Wti, 0, bi, 0, nullptr, yp, 256);
    mix_init<<<512, 256, 0, stream>>>(yp, G, xi2, l2cat, c1, c2);

    // ---- T sequential steps ----
    for (int t = 0; t < Tt; t++) {
        gemm_mfma<2, 4><<<dim3(8, 4, 24), 256, 0, stream>>>(
            xi2, nullptr, 192, Wt0, (size_t)512 * 192, nullptr, 0, base1, yp, 512);
        mixlstm<<<dim3(512, 2), 256, 0, stream>>>(yp, G, c1, xi2 + 8, 192, l2cat, 256, 0);
        gemm_mfma<2, 4><<<dim3(8, 4, 24), 256, 0, stream>>>(
            l2cat, nullptr, 256, Wt1, (size_t)512 * 256, b1i, 512, nullptr, yp, 512);
        mixlstm<<<dim3(512, 2), 256, 0, stream>>>(yp, G, c2, l2cat + 128, 256, yib, 128, 1);
        gemm_mfma<2, 4><<<dim3(4, 4, 24), 256, 0, stream>>>(
            yib, nullptr, 128, Wtf, (size_t)256 * 128, bcat, 256, nullptr, pbuf, 256);
        finstep<<<512, 256, 0, stream>>>(pbuf, G, locW, locb, lzW, lzb, ls, xi2, out, t);
    }
}

// Round 7
// 2844.358 us; speedup vs baseline: 1.1190x; 1.1190x over previous
//
#include <hip/hip_runtime.h>
#include <math.h>

#define Bsz 512
#define Nn  24
#define Tt  25
// IN=8, L=64, H=256, OUT=128
// layer1: per-step K = 8(loc,locd) + 128(h1) -> padded 192; z-part hoisted to base1
// layer2: K=256; fc: K=128; init: K=256 from enc (fp32)

typedef _Float16 f16;
typedef _Float16 f16x8 __attribute__((ext_vector_type(8)));
typedef _Float16 f16x4 __attribute__((ext_vector_type(4)));
typedef float f32x4 __attribute__((ext_vector_type(4)));

// ---------------------------------------------------------------------------
// MFMA fp16 GEMM, per-node block-diagonal, W-as-A orientation (verified R4):
//   Y[b,n,o] = sum_k Act[b,n,k] * W[n,o,k] + bias[n,o] (+ base16[b,n,o])
// Register-prefetch pipelined K-loop.
// ---------------------------------------------------------------------------
template <int FM, int FN>
__global__ __launch_bounds__(256) void gemm_mfma(
    const f16* __restrict__ Act, const float* __restrict__ Act32, int Ka,
    const f16* __restrict__ W, size_t wstride,
    const float* __restrict__ bias, int bstride,
    const f16* __restrict__ base16,
    f16* __restrict__ Y, int O)
{
    const int BM = FM * 32, BN = FN * 32;
    const int n  = blockIdx.z;
    const int o0 = blockIdx.x * BM;
    const int b0 = blockIdx.y * BN;
    const int tid  = threadIdx.x;
    const int wave = tid >> 6, lane = tid & 63;
    const int wm = (wave >> 1) * FM * 16;   // o offset of wave
    const int wn = (wave & 1) * FN * 16;    // b offset of wave
    const int m16 = lane & 15, quad = lane >> 4;

    __shared__ __attribute__((aligned(16))) f16 sW[BM][72];  // o-rows, k-cols (+pad)
    __shared__ __attribute__((aligned(16))) f16 sB[BN][72];  // b-rows, k-cols

    const f16* Wn = W + (size_t)n * wstride;
    f32x4 acc[FM][FN] = {};

    const int r  = tid >> 3;        // staging row 0..31
    const int cc = (tid & 7) * 8;   // staging col (halfs)
    const int nk = Ka >> 6;         // 64-wide k tiles

    f16x8 rW[FM], rB[FN];
    float rBf[FN][8];

    // ---- prefetch k-tile 0 into registers ----
#pragma unroll
    for (int i = 0; i < FM; i++)
        rW[i] = *(const f16x8*)&Wn[(size_t)(o0 + r + 32 * i) * Ka + cc];
    if (Act) {
#pragma unroll
        for (int j = 0; j < FN; j++)
            rB[j] = *(const f16x8*)&Act[((size_t)(b0 + r + 32 * j) * Nn + n) * Ka + cc];
    } else {
#pragma unroll
        for (int j = 0; j < FN; j++) {
            const float* src = &Act32[((size_t)(b0 + r + 32 * j) * Nn + n) * Ka + cc];
#pragma unroll
            for (int u = 0; u < 8; u++) rBf[j][u] = src[u];
        }
    }

    for (int it = 0; it < nk; it++) {
        // ---- commit prefetched tile to LDS ----
#pragma unroll
        for (int i = 0; i < FM; i++)
            *(f16x8*)&sW[r + 32 * i][cc] = rW[i];
        if (Act) {
#pragma unroll
            for (int j = 0; j < FN; j++)
                *(f16x8*)&sB[r + 32 * j][cc] = rB[j];
        } else {
#pragma unroll
            for (int j = 0; j < FN; j++) {
                f16x8 v;
#pragma unroll
                for (int u = 0; u < 8; u++) v[u] = (f16)rBf[j][u];
                *(f16x8*)&sB[r + 32 * j][cc] = v;
            }
        }
        __syncthreads();

        // ---- issue next tile's global loads (latency hides under MFMA) ----
        if (it + 1 < nk) {
            const int k0n = (it + 1) << 6;
#pragma unroll
            for (int i = 0; i < FM; i++)
                rW[i] = *(const f16x8*)&Wn[(size_t)(o0 + r + 32 * i) * Ka + k0n + cc];
            if (Act) {
#pragma unroll
                for (int j = 0; j < FN; j++)
                    rB[j] = *(const f16x8*)&Act[((size_t)(b0 + r + 32 * j) * Nn + n) * Ka + k0n + cc];
            } else {
#pragma unroll
                for (int j = 0; j < FN; j++) {
                    const float* src = &Act32[((size_t)(b0 + r + 32 * j) * Nn + n) * Ka + k0n + cc];
#pragma unroll
                    for (int u = 0; u < 8; u++) rBf[j][u] = src[u];
                }
            }
        }

        // ---- MFMA on the committed LDS tile ----
#pragma unroll
        for (int kk = 0; kk < 64; kk += 32) {
            f16x8 af[FM], bf[FN];
#pragma unroll
            for (int i = 0; i < FM; i++)
                af[i] = *(const f16x8*)&sW[wm + i * 16 + m16][kk + quad * 8];
#pragma unroll
            for (int j = 0; j < FN; j++)
                bf[j] = *(const f16x8*)&sB[wn + j * 16 + m16][kk + quad * 8];
#pragma unroll
            for (int i = 0; i < FM; i++)
#pragma unroll
                for (int j = 0; j < FN; j++)
                    acc[i][j] = __builtin_amdgcn_mfma_f32_16x16x32_f16(af[i], bf[j], acc[i][j], 0, 0, 0);
        }
        __syncthreads();
    }
    // epilogue: D[row=o][col=b]; per lane, regs = 4 consecutive o at quad*4
#pragma unroll
    for (int i = 0; i < FM; i++) {
        const int orow = o0 + wm + i * 16 + quad * 4;
        float4 bv = make_float4(0.f, 0.f, 0.f, 0.f);
        if (bias) bv = *(const float4*)&bias[(size_t)n * bstride + orow];
#pragma unroll
        for (int j = 0; j < FN; j++) {
            const int bcol = b0 + wn + j * 16 + m16;
            size_t yi = ((size_t)bcol * Nn + n) * (size_t)O + orow;
            float v0 = acc[i][j][0] + bv.x;
            float v1 = acc[i][j][1] + bv.y;
            float v2 = acc[i][j][2] + bv.z;
            float v3 = acc[i][j][3] + bv.w;
            if (base16) {
                f16x4 bb = *(const f16x4*)&base16[yi];
                v0 += (float)bb[0]; v1 += (float)bb[1];
                v2 += (float)bb[2]; v3 += (float)bb[3];
            }
            f16x4 o4; o4[0] = (f16)v0; o4[1] = (f16)v1; o4[2] = (f16)v2; o4[3] = (f16)v3;
            *(f16x4*)&Y[yi] = o4;
        }
    }
}

// ---------------------------------------------------------------------------
// Weight prep: Wz (24,512,64)=Wx0[:, :64, :]^T; Wt0 (24,512,192)=[Wx0[64:72]|Wh0|0]^T;
// Wt1 (24,512,256)=[Wx1|Wh1]^T
// ---------------------------------------------------------------------------
__global__ __launch_bounds__(256) void prep_w01(
    const float* __restrict__ Wx0, const float* __restrict__ Wh0,
    const float* __restrict__ Wx1, const float* __restrict__ Wh1,
    f16* __restrict__ Wz, f16* __restrict__ Wt0, f16* __restrict__ Wt1)
{
    size_t idx = (size_t)blockIdx.x * 256 + threadIdx.x;
    const size_t nz = (size_t)Nn * 512 * 64;       // 786432
    const size_t n0 = (size_t)Nn * 512 * 192;      // 2359296
    const size_t n1 = (size_t)Nn * 512 * 256;      // 3145728
    if (idx < nz) {
        int k = idx & 63; int o = (idx >> 6) & 511; int n = (int)(idx >> 15);
        Wz[idx] = (f16)Wx0[((size_t)n * 72 + k) * 512 + o];
    } else if (idx < nz + n0) {
        size_t i2 = idx - nz;
        int k = (int)(i2 % 192);
        size_t no = i2 / 192;
        int o = (int)(no & 511); int n = (int)(no >> 9);
        float v = 0.f;
        if (k < 8) v = Wx0[((size_t)n * 72 + 64 + k) * 512 + o];
        else if (k < 136) v = Wh0[((size_t)n * 128 + (k - 8)) * 512 + o];
        Wt0[i2] = (f16)v;
    } else if (idx < nz + n0 + n1) {
        size_t i3 = idx - nz - n0;
        int k = (int)(i3 & 255);
        size_t no = i3 >> 8;
        int o = (int)(no & 511); int n = (int)(no >> 9);
        float v = (k < 128) ? Wx1[((size_t)n * 128 + k) * 512 + o]
                            : Wh1[((size_t)n * 128 + (k - 128)) * 512 + o];
        Wt1[i3] = (f16)v;
    }
}

// Wtf (24,256,128): o<128 -> fcW^T, else fc2W^T
__global__ __launch_bounds__(256) void prep_wf(
    const float* __restrict__ fcW, const float* __restrict__ fc2W,
    f16* __restrict__ Wtf)
{
    size_t idx = (size_t)blockIdx.x * 256 + threadIdx.x;
    if (idx >= (size_t)Nn * 256 * 128) return;
    int k = (int)(idx & 127);
    size_t no = idx >> 7;
    int o = (int)(no & 255); int n = (int)(no >> 8);
    float v = (o < 128) ? fcW[((size_t)n * 128 + k) * 128 + o]
                        : fc2W[((size_t)n * 128 + k) * 128 + (o - 128)];
    Wtf[idx] = (f16)v;
}

// Wti (256,256) = [ih1W | ih2W]^T ; bi (256) ; bcat (24,256)
__global__ __launch_bounds__(256) void prep_wi(
    const float* __restrict__ ih1W, const float* __restrict__ ih2W,
    const float* __restrict__ ih1b, const float* __restrict__ ih2b,
    const float* __restrict__ fcb, const float* __restrict__ fc2b,
    f16* __restrict__ Wti, float* __restrict__ bi, float* __restrict__ bcat)
{
    int idx = blockIdx.x * 256 + threadIdx.x;   // 65536
    int k = idx & 255, o = idx >> 8;
    Wti[idx] = (f16)((o < 128) ? ih1W[(size_t)k * 128 + o] : ih2W[(size_t)k * 128 + (o - 128)]);
    if (idx < 256) bi[idx] = (idx < 128) ? ih1b[idx] : ih2b[idx - 128];
    if (idx < Nn * 256) {
        int n = idx >> 8, oo = idx & 255;
        bcat[idx] = (oo < 128) ? fcb[n * 128 + oo] : fc2b[n * 128 + (oo - 128)];
    }
}

// xi2[b,n,0:8)=x, [136:192)=0 ([8:136) = h1, filled by mix_init/mixlstm); ls=x[:4]
__global__ __launch_bounds__(256) void init_xi(
    const float* __restrict__ x, f16* __restrict__ xi2, float* __restrict__ ls)
{
    size_t idx = (size_t)blockIdx.x * 256 + threadIdx.x;
    const size_t total = (size_t)Bsz * Nn * 192;
    if (idx < total) {
        size_t bn = idx / 192;
        int k = (int)(idx - bn * 192);
        if (k < 8) xi2[idx] = (f16)x[bn * 8 + k];
        else if (k >= 136) xi2[idx] = (f16)0.f;
    }
    if (idx < (size_t)Bsz * Nn * 4) {
        size_t bn = idx >> 2;
        ls[idx] = x[bn * 8 + (idx & 3)];
    }
}

// ---------------------------------------------------------------------------
// Init mix (exact R4 source): Yhc (B,N,256) f16 = [h-pre | c-pre].
// ---------------------------------------------------------------------------
__global__ __launch_bounds__(256) void mix_init(
    const f16* __restrict__ Yhc, const float* __restrict__ G,
    f16* __restrict__ xi2, f16* __restrict__ l2cat,
    float* __restrict__ c1, float* __restrict__ c2)
{
    const int b = blockIdx.x;
    const int tid = threadIdx.x;
    __shared__ float sY[6144], sG[576];
    for (int i = tid; i < 576; i += 256) sG[i] = G[i];
    for (int v = tid; v < 768; v += 256) {
        int c8 = (v & 31) * 8, n = v >> 5;
        f16x8 t = *(const f16x8*)&Yhc[((size_t)b * Nn + n) * 256 + c8];
        float* d = &sY[n * 256 + c8];
#pragma unroll
        for (int u = 0; u < 8; u++) d[u] = (float)t[u];
    }
    __syncthreads();
    for (int w = tid; w < 3072; w += 256) {
        int o = w & 127, m = w >> 7;
        float ah = 0.f, ac = 0.f;
#pragma unroll
        for (int n = 0; n < 24; n++) {
            float g = sG[m * 24 + n];
            ah += g * sY[n * 256 + o];
            ac += g * sY[n * 256 + 128 + o];
        }
        size_t row = (size_t)b * Nn + m;
        f16 hf = (f16)ah;
        xi2[row * 192 + 8 + o] = hf;
        l2cat[row * 256 + o] = hf;
        l2cat[row * 256 + 128 + o] = hf;
        c1[row * 128 + o] = ac;
        c2[row * 128 + o] = ac;
    }
}

// ---------------------------------------------------------------------------
// G-mix + LSTM pointwise. Ypre (B,N,512) f16 pre-mix gates. c fp32 in/out.
// SCRATCH-PROOF hoisted version: j = tid&63 is constant per thread, so the 4
// gate values sY[n*256+g*64+j] are read ONCE per n and reused across this
// thread's 6 m outputs via 24 individually NAMED scalar accumulators (no
// arrays -> guaranteed VGPRs, rule #20). Per-output accumulation order is
// n-ascending single-accumulator, same as R4.
// LDS reads/thread: 720 (R4) -> 240.
// ---------------------------------------------------------------------------
__global__ __launch_bounds__(256) void mixlstm(
    const f16* __restrict__ Ypre, const float* __restrict__ G,
    float* __restrict__ c,
    f16* __restrict__ dstA, int strideA,
    f16* __restrict__ dstB, int strideB, int tanhB)
{
    const int b = blockIdx.x;
    const int jt = blockIdx.y * 64;
    const int tid = threadIdx.x;
    __shared__ float sY[6144];   // n, gate, j(64)
    __shared__ float sG[576];
    for (int i = tid; i < 576; i += 256) sG[i] = G[i];
    for (int v = tid; v < 768; v += 256) {
        int j8 = (v & 7) * 8, g = (v >> 3) & 3, n = v >> 5;
        f16x8 t = *(const f16x8*)&Ypre[((size_t)b * Nn + n) * 512 + g * 128 + jt + j8];
        float* d = &sY[n * 256 + g * 64 + j8];
#pragma unroll
        for (int u = 0; u < 8; u++) d[u] = (float)t[u];
    }
    __syncthreads();

    const int j  = tid & 63;
    const int mg = tid >> 6;            // m = mg + 4k, k = 0..5
    const float* gb = &sG[mg * 24];     // row stride 4*24 = 96 floats

    float s00 = 0.f, s01 = 0.f, s02 = 0.f, s03 = 0.f;
    float s10 = 0.f, s11 = 0.f, s12 = 0.f, s13 = 0.f;
    float s20 = 0.f, s21 = 0.f, s22 = 0.f, s23 = 0.f;
    float s30 = 0.f, s31 = 0.f, s32 = 0.f, s33 = 0.f;
    float s40 = 0.f, s41 = 0.f, s42 = 0.f, s43 = 0.f;
    float s50 = 0.f, s51 = 0.f, s52 = 0.f, s53 = 0.f;

    for (int n = 0; n < 24; n++) {
        const float* yr = &sY[n * 256 + j];
        float y0 = yr[0];
        float y1 = yr[64];
        float y2 = yr[128];
        float y3 = yr[192];
        float g0 = gb[n];
        float g1 = gb[96 + n];
        float g2 = gb[192 + n];
        float g3 = gb[288 + n];
        float g4 = gb[384 + n];
        float g5 = gb[480 + n];
        s00 += g0 * y0; s01 += g0 * y1; s02 += g0 * y2; s03 += g0 * y3;
        s10 += g1 * y0; s11 += g1 * y1; s12 += g1 * y2; s13 += g1 * y3;
        s20 += g2 * y0; s21 += g2 * y1; s22 += g2 * y2; s23 += g2 * y3;
        s30 += g3 * y0; s31 += g3 * y1; s32 += g3 * y2; s33 += g3 * y3;
        s40 += g4 * y0; s41 += g4 * y1; s42 += g4 * y2; s43 += g4 * y3;
        s50 += g5 * y0; s51 += g5 * y1; s52 += g5 * y2; s53 += g5 * y3;
    }

    const int col = jt + j;
    auto fin = [&](int m, float gi, float gf, float gg, float go) {
        size_t row = (size_t)b * Nn + m;
        float cv = c[row * 128 + col];
        float si = 1.f / (1.f + expf(-gi));
        float sf = 1.f / (1.f + expf(-gf));
        float so = 1.f / (1.f + expf(-go));
        float tg = tanhf(gg);
        cv = sf * cv + si * tg;
        c[row * 128 + col] = cv;
        float h = so * tanhf(cv);
        dstA[row * strideA + col] = (f16)h;
        dstB[row * strideB + col] = (f16)(tanhB ? tanhf(h) : h);
    };
    fin(mg,      s00, s01, s02, s03);
    fin(mg + 4,  s10, s11, s12, s13);
    fin(mg + 8,  s20, s21, s22, s23);
    fin(mg + 12, s30, s31, s32, s33);
    fin(mg + 16, s40, s41, s42, s43);
    fin(mg + 20, s50, s51, s52, s53);
}

// ---------------------------------------------------------------------------
// Final per-step (exact R4 source): mix fc pre-acts + tanh, head matvecs,
// second mix, quat, outputs, update xi2[0:8) & loc_start.
// ---------------------------------------------------------------------------
__global__ __launch_bounds__(256) void finstep(
    const f16* __restrict__ p, const float* __restrict__ G,
    const float* __restrict__ locW, const float* __restrict__ locb,
    const float* __restrict__ lzW, const float* __restrict__ lzb,
    float* __restrict__ ls, f16* __restrict__ xi2,
    float* __restrict__ out, int t)
{
    const int b = blockIdx.x;
    const int tid = threadIdx.x;
    __shared__ float sP[6144], sY1[3072], sY2[3072];
    __shared__ float sG[576];
    __shared__ float sLp[24][3], sZp[24][4], sL3[24][3], sZ3[24][4];
    for (int i = tid; i < 576; i += 256) sG[i] = G[i];
    for (int v = tid; v < 768; v += 256) {
        int c8 = (v & 31) * 8, n = v >> 5;
        f16x8 tv = *(const f16x8*)&p[((size_t)b * Nn + n) * 256 + c8];
        float* d = &sP[n * 256 + c8];
#pragma unroll
        for (int u = 0; u < 8; u++) d[u] = (float)tv[u];
    }
    __syncthreads();
    for (int w = tid; w < 3072; w += 256) {
        int o = w & 127, m = w >> 7;
        float a1 = 0.f, a2 = 0.f;
#pragma unroll
        for (int n = 0; n < 24; n++) {
            float g = sG[m * 24 + n];
            a1 += g * sP[n * 256 + o];
            a2 += g * sP[n * 256 + 128 + o];
        }
        sY1[w] = tanhf(a1);
        sY2[w] = tanhf(a2);
    }
    __syncthreads();
    if (tid < 72) {
        int m = tid / 3, j = tid - m * 3;
        float s = locb[j];
        for (int o = 0; o < 128; o++) s += sY1[m * 128 + o] * locW[o * 3 + j];
        sLp[m][j] = s;
    } else if (tid < 168) {
        int w2 = tid - 72; int m = w2 >> 2, j = w2 & 3;
        float s = lzb[j];
        for (int o = 0; o < 128; o++) s += sY2[m * 128 + o] * lzW[o * 4 + j];
        sZp[m][j] = s;
    }
    __syncthreads();
    if (tid < 72) {
        int m = tid / 3, j = tid - m * 3;
        float s = 0.f;
#pragma unroll
        for (int n = 0; n < 24; n++) s += sG[m * 24 + n] * sLp[n][j];
        sL3[m][j] = s;
    } else if (tid < 168) {
        int w2 = tid - 72; int m = w2 >> 2, j = w2 & 3;
        float s = 0.f;
#pragma unroll
        for (int n = 0; n < 24; n++) s += sG[m * 24 + n] * sZp[n][j];
        sZ3[m][j] = s;
    }
    __syncthreads();
    if (tid < 24) {
        int m = tid;
        float xx = sL3[m][0], xy = sL3[m][1], xz = sL3[m][2];
        float r = rsqrtf(1.f + xx * xx + xy * xy + xz * xz);
        float dw = r, dx = xx * r, dy = xy * r, dz = xz * r;
        size_t li = ((size_t)b * Nn + m) * 4;
        float qw = ls[li], qx = ls[li + 1], qy = ls[li + 2], qz = ls[li + 3];
        float lw = qw * dw - qx * dx - qy * dy - qz * dz;
        float lx = qw * dx + qx * dw + qy * dz - qz * dy;
        float ly = qw * dy - qx * dz + qy * dw + qz * dx;
        float lz = qw * dz + qx * dy - qy * dx + qz * dw;
        size_t oi = (((size_t)b * Tt + t) * Nn + m) * 4;
        out[oi + 0] = lw; out[oi + 1] = lx; out[oi + 2] = ly; out[oi + 3] = lz;
        size_t zi = (size_t)Bsz * Tt * Nn * 4 + oi;
        out[zi + 0] = sZ3[m][0]; out[zi + 1] = sZ3[m][1];
        out[zi + 2] = sZ3[m][2]; out[zi + 3] = sZ3[m][3];
        ls[li] = lw; ls[li + 1] = lx; ls[li + 2] = ly; ls[li + 3] = lz;
        size_t xb = ((size_t)b * Nn + m) * 192;
        xi2[xb + 0] = (f16)lw; xi2[xb + 1] = (f16)lx; xi2[xb + 2] = (f16)ly; xi2[xb + 3] = (f16)lz;
        xi2[xb + 4] = (f16)dw; xi2[xb + 5] = (f16)dx; xi2[xb + 6] = (f16)dy; xi2[xb + 7] = (f16)dz;
    }
}

extern "C" void kernel_launch(void* const* d_in, const int* in_sizes, int n_in,
                              void* d_out, int out_size, void* d_ws, size_t ws_size,
                              hipStream_t stream)
{
    const float* x    = (const float*)d_in[0];
    const float* enc  = (const float*)d_in[1];
    const float* z    = (const float*)d_in[2];
    const float* G    = (const float*)d_in[4];
    const float* Wx0  = (const float*)d_in[5];
    const float* Wh0  = (const float*)d_in[6];
    const float* b0i  = (const float*)d_in[7];
    const float* Wx1  = (const float*)d_in[8];
    const float* Wh1  = (const float*)d_in[9];
    const float* b1i  = (const float*)d_in[10];
    const float* fcW  = (const float*)d_in[11];
    const float* fcb  = (const float*)d_in[12];
    const float* fc2W = (const float*)d_in[13];
    const float* fc2b = (const float*)d_in[14];
    const float* ih1W = (const float*)d_in[15];
    const float* ih1b = (const float*)d_in[16];
    const float* ih2W = (const float*)d_in[17];
    const float* ih2b = (const float*)d_in[18];
    const float* locW = (const float*)d_in[19];
    const float* locb = (const float*)d_in[20];
    const float* lzW  = (const float*)d_in[21];
    const float* lzb  = (const float*)d_in[22];
    float* out = (float*)d_out;

    const size_t BN = (size_t)Bsz * Nn;
    char* wp = (char*)d_ws;
    size_t off = 0;
    auto carve = [&](size_t bytes) -> char* {
        char* pc = wp + off;
        off += (bytes + 255) & ~(size_t)255;
        return pc;
    };
    f16*   Wz     = (f16*)carve((size_t)Nn * 512 * 64 * 2);
    f16*   Wt0    = (f16*)carve((size_t)Nn * 512 * 192 * 2);
    f16*   Wt1    = (f16*)carve((size_t)Nn * 512 * 256 * 2);
    f16*   Wtf    = (f16*)carve((size_t)Nn * 256 * 128 * 2);
    f16*   Wti    = (f16*)carve((size_t)256 * 256 * 2);
    float* bcat   = (float*)carve((size_t)Nn * 256 * 4);
    float* bi     = (float*)carve(256 * 4);
    f16*   base1  = (f16*)carve(BN * 512 * 2);
    f16*   xi2    = (f16*)carve(BN * 192 * 2);
    f16*   l2cat  = (f16*)carve(BN * 256 * 2);
    f16*   yib    = (f16*)carve(BN * 128 * 2);
    float* c1     = (float*)carve(BN * 128 * 4);
    float* c2     = (float*)carve(BN * 128 * 4);
    float* ls     = (float*)carve(BN * 4 * 4);
    f16*   yp     = (f16*)carve(BN * 512 * 2);
    f16*   pbuf   = (f16*)carve(BN * 256 * 2);

    // ---- one-time prep ----
    prep_w01<<<24576, 256, 0, stream>>>(Wx0, Wh0, Wx1, Wh1, Wz, Wt0, Wt1);
    prep_wf<<<3072, 256, 0, stream>>>(fcW, fc2W, Wtf);
    prep_wi<<<256, 256, 0, stream>>>(ih1W, ih2W, ih1b, ih2b, fcb, fc2b, Wti, bi, bcat);
    init_xi<<<9216, 256, 0, stream>>>(x, xi2, ls);

    // base1 = z . Wx0[:,:64,:] + b0    (constant over all T steps)
    gemm_mfma<2, 4><<<dim3(8, 4, 24), 256, 0, stream>>>(
        nullptr, z, 64, Wz, (size_t)512 * 64, b0i, 512, nullptr, base1, 512);
    // init states: [h0|c0] from enc
    gemm_mfma<2, 4><<<dim3(4, 4, 24), 256, 0, stream>>>(
        nullptr, enc, 256, Wti, 0, bi, 0, nullptr, yp, 256);
    mix_init<<<512, 256, 0, stream>>>(yp, G, xi2, l2cat, c1, c2);

    // ---- T sequential steps ----
    for (int t = 0; t < Tt; t++) {
        gemm_mfma<2, 4><<<dim3(8, 4, 24), 256, 0, stream>>>(
            xi2, nullptr, 192, Wt0, (size_t)512 * 192, nullptr, 0, base1, yp, 512);
        mixlstm<<<dim3(512, 2), 256, 0, stream>>>(yp, G, c1, xi2 + 8, 192, l2cat, 256, 0);
        gemm_mfma<2, 4><<<dim3(8, 4, 24), 256, 0, stream>>>(
            l2cat, nullptr, 256, Wt1, (size_t)512 * 256, b1i, 512, nullptr, yp, 512);
        mixlstm<<<dim3(512, 2), 256, 0, stream>>>(yp, G, c2, l2cat + 128, 256, yib, 128, 1);
        gemm_mfma<2, 4><<<dim3(4, 4, 24), 256, 0, stream>>>(
            yib, nullptr, 128, Wtf, (size_t)256 * 128, bcat, 256, nullptr, pbuf, 256);
        finstep<<<512, 256, 0, stream>>>(pbuf, G, locW, locb, lzW, lzb, ls, xi2, out, t);
    }
}

// Round 8
// 2351.870 us; speedup vs baseline: 1.3533x; 1.2094x over previous
//
#include <hip/hip_runtime.h>
#include <math.h>

#define Bsz 512
#define Nn  24
#define Tt  25
// IN=8, L=64, H=256, OUT=128
// layer1: per-step K = 8(loc,locd) + 128(h1) -> padded 192; z-part hoisted to base1
// layer2: K=256; fc: K=128; init: K=256 from enc (fp32)

typedef _Float16 f16;
typedef _Float16 f16x8 __attribute__((ext_vector_type(8)));
typedef _Float16 f16x4 __attribute__((ext_vector_type(4)));
typedef float f32x4 __attribute__((ext_vector_type(4)));

// ---------------------------------------------------------------------------
// MFMA fp16 GEMM, per-node block-diagonal, W-as-A orientation (verified R4):
//   Y[b,n,o] = sum_k Act[b,n,k] * W[n,o,k] + bias[n,o] (+ base16[b,n,o])
// Register-prefetch pipelined K-loop: loads for tile k+1 issue before the
// MFMA block of tile k.
// ---------------------------------------------------------------------------
template <int FM, int FN>
__global__ __launch_bounds__(256) void gemm_mfma(
    const f16* __restrict__ Act, const float* __restrict__ Act32, int Ka,
    const f16* __restrict__ W, size_t wstride,
    const float* __restrict__ bias, int bstride,
    const f16* __restrict__ base16,
    f16* __restrict__ Y, int O)
{
    const int BM = FM * 32, BN = FN * 32;
    const int n  = blockIdx.z;
    const int o0 = blockIdx.x * BM;
    const int b0 = blockIdx.y * BN;
    const int tid  = threadIdx.x;
    const int wave = tid >> 6, lane = tid & 63;
    const int wm = (wave >> 1) * FM * 16;   // o offset of wave
    const int wn = (wave & 1) * FN * 16;    // b offset of wave
    const int m16 = lane & 15, quad = lane >> 4;

    __shared__ __attribute__((aligned(16))) f16 sW[BM][72];  // o-rows, k-cols (+pad)
    __shared__ __attribute__((aligned(16))) f16 sB[BN][72];  // b-rows, k-cols

    const f16* Wn = W + (size_t)n * wstride;
    f32x4 acc[FM][FN] = {};

    const int r  = tid >> 3;        // staging row 0..31
    const int cc = (tid & 7) * 8;   // staging col (halfs)
    const int nk = Ka >> 6;         // 64-wide k tiles

    f16x8 rW[FM], rB[FN];
    float rBf[FN][8];

    // ---- prefetch k-tile 0 into registers ----
#pragma unroll
    for (int i = 0; i < FM; i++)
        rW[i] = *(const f16x8*)&Wn[(size_t)(o0 + r + 32 * i) * Ka + cc];
    if (Act) {
#pragma unroll
        for (int j = 0; j < FN; j++)
            rB[j] = *(const f16x8*)&Act[((size_t)(b0 + r + 32 * j) * Nn + n) * Ka + cc];
    } else {
#pragma unroll
        for (int j = 0; j < FN; j++) {
            const float* src = &Act32[((size_t)(b0 + r + 32 * j) * Nn + n) * Ka + cc];
#pragma unroll
            for (int u = 0; u < 8; u++) rBf[j][u] = src[u];
        }
    }

    for (int it = 0; it < nk; it++) {
        // ---- commit prefetched tile to LDS ----
#pragma unroll
        for (int i = 0; i < FM; i++)
            *(f16x8*)&sW[r + 32 * i][cc] = rW[i];
        if (Act) {
#pragma unroll
            for (int j = 0; j < FN; j++)
                *(f16x8*)&sB[r + 32 * j][cc] = rB[j];
        } else {
#pragma unroll
            for (int j = 0; j < FN; j++) {
                f16x8 v;
#pragma unroll
                for (int u = 0; u < 8; u++) v[u] = (f16)rBf[j][u];
                *(f16x8*)&sB[r + 32 * j][cc] = v;
            }
        }
        __syncthreads();

        // ---- issue next tile's global loads (latency hides under MFMA) ----
        if (it + 1 < nk) {
            const int k0n = (it + 1) << 6;
#pragma unroll
            for (int i = 0; i < FM; i++)
                rW[i] = *(const f16x8*)&Wn[(size_t)(o0 + r + 32 * i) * Ka + k0n + cc];
            if (Act) {
#pragma unroll
                for (int j = 0; j < FN; j++)
                    rB[j] = *(const f16x8*)&Act[((size_t)(b0 + r + 32 * j) * Nn + n) * Ka + k0n + cc];
            } else {
#pragma unroll
                for (int j = 0; j < FN; j++) {
                    const float* src = &Act32[((size_t)(b0 + r + 32 * j) * Nn + n) * Ka + k0n + cc];
#pragma unroll
                    for (int u = 0; u < 8; u++) rBf[j][u] = src[u];
                }
            }
        }

        // ---- MFMA on the committed LDS tile ----
#pragma unroll
        for (int kk = 0; kk < 64; kk += 32) {
            f16x8 af[FM], bf[FN];
#pragma unroll
            for (int i = 0; i < FM; i++)
                af[i] = *(const f16x8*)&sW[wm + i * 16 + m16][kk + quad * 8];
#pragma unroll
            for (int j = 0; j < FN; j++)
                bf[j] = *(const f16x8*)&sB[wn + j * 16 + m16][kk + quad * 8];
#pragma unroll
            for (int i = 0; i < FM; i++)
#pragma unroll
                for (int j = 0; j < FN; j++)
                    acc[i][j] = __builtin_amdgcn_mfma_f32_16x16x32_f16(af[i], bf[j], acc[i][j], 0, 0, 0);
        }
        __syncthreads();
    }
    // epilogue: D[row=o][col=b]; per lane, regs = 4 consecutive o at quad*4
#pragma unroll
    for (int i = 0; i < FM; i++) {
        const int orow = o0 + wm + i * 16 + quad * 4;
        float4 bv = make_float4(0.f, 0.f, 0.f, 0.f);
        if (bias) bv = *(const float4*)&bias[(size_t)n * bstride + orow];
#pragma unroll
        for (int j = 0; j < FN; j++) {
            const int bcol = b0 + wn + j * 16 + m16;
            size_t yi = ((size_t)bcol * Nn + n) * (size_t)O + orow;
            float v0 = acc[i][j][0] + bv.x;
            float v1 = acc[i][j][1] + bv.y;
            float v2 = acc[i][j][2] + bv.z;
            float v3 = acc[i][j][3] + bv.w;
            if (base16) {
                f16x4 bb = *(const f16x4*)&base16[yi];
                v0 += (float)bb[0]; v1 += (float)bb[1];
                v2 += (float)bb[2]; v3 += (float)bb[3];
            }
            f16x4 o4; o4[0] = (f16)v0; o4[1] = (f16)v1; o4[2] = (f16)v2; o4[3] = (f16)v3;
            *(f16x4*)&Y[yi] = o4;
        }
    }
}

// ---------------------------------------------------------------------------
// Weight prep: Wz (24,512,64)=Wx0[:, :64, :]^T; Wt0 (24,512,192)=[Wx0[64:72]|Wh0|0]^T;
// Wt1 (24,512,256)=[Wx1|Wh1]^T
// ---------------------------------------------------------------------------
__global__ __launch_bounds__(256) void prep_w01(
    const float* __restrict__ Wx0, const float* __restrict__ Wh0,
    const float* __restrict__ Wx1, const float* __restrict__ Wh1,
    f16* __restrict__ Wz, f16* __restrict__ Wt0, f16* __restrict__ Wt1)
{
    size_t idx = (size_t)blockIdx.x * 256 + threadIdx.x;
    const size_t nz = (size_t)Nn * 512 * 64;       // 786432
    const size_t n0 = (size_t)Nn * 512 * 192;      // 2359296
    const size_t n1 = (size_t)Nn * 512 * 256;      // 3145728
    if (idx < nz) {
        int k = idx & 63; int o = (idx >> 6) & 511; int n = (int)(idx >> 15);
        Wz[idx] = (f16)Wx0[((size_t)n * 72 + k) * 512 + o];
    } else if (idx < nz + n0) {
        size_t i2 = idx - nz;
        int k = (int)(i2 % 192);
        size_t no = i2 / 192;
        int o = (int)(no & 511); int n = (int)(no >> 9);
        float v = 0.f;
        if (k < 8) v = Wx0[((size_t)n * 72 + 64 + k) * 512 + o];
        else if (k < 136) v = Wh0[((size_t)n * 128 + (k - 8)) * 512 + o];
        Wt0[i2] = (f16)v;
    } else if (idx < nz + n0 + n1) {
        size_t i3 = idx - nz - n0;
        int k = (int)(i3 & 255);
        size_t no = i3 >> 8;
        int o = (int)(no & 511); int n = (int)(no >> 9);
        float v = (k < 128) ? Wx1[((size_t)n * 128 + k) * 512 + o]
                            : Wh1[((size_t)n * 128 + (k - 128)) * 512 + o];
        Wt1[i3] = (f16)v;
    }
}

// Wtf (24,256,128): o<128 -> fcW^T, else fc2W^T
__global__ __launch_bounds__(256) void prep_wf(
    const float* __restrict__ fcW, const float* __restrict__ fc2W,
    f16* __restrict__ Wtf)
{
    size_t idx = (size_t)blockIdx.x * 256 + threadIdx.x;
    if (idx >= (size_t)Nn * 256 * 128) return;
    int k = (int)(idx & 127);
    size_t no = idx >> 7;
    int o = (int)(no & 255); int n = (int)(no >> 8);
    float v = (o < 128) ? fcW[((size_t)n * 128 + k) * 128 + o]
                        : fc2W[((size_t)n * 128 + k) * 128 + (o - 128)];
    Wtf[idx] = (f16)v;
}

// Wti (256,256) = [ih1W | ih2W]^T ; bi (256) ; bcat (24,256)
__global__ __launch_bounds__(256) void prep_wi(
    const float* __restrict__ ih1W, const float* __restrict__ ih2W,
    const float* __restrict__ ih1b, const float* __restrict__ ih2b,
    const float* __restrict__ fcb, const float* __restrict__ fc2b,
    f16* __restrict__ Wti, float* __restrict__ bi, float* __restrict__ bcat)
{
    int idx = blockIdx.x * 256 + threadIdx.x;   // 65536
    int k = idx & 255, o = idx >> 8;
    Wti[idx] = (f16)((o < 128) ? ih1W[(size_t)k * 128 + o] : ih2W[(size_t)k * 128 + (o - 128)]);
    if (idx < 256) bi[idx] = (idx < 128) ? ih1b[idx] : ih2b[idx - 128];
    if (idx < Nn * 256) {
        int n = idx >> 8, oo = idx & 255;
        bcat[idx] = (oo < 128) ? fcb[n * 128 + oo] : fc2b[n * 128 + (oo - 128)];
    }
}

// xi2[b,n,0:8)=x, [136:192)=0 ([8:136) = h1, filled by mix_init/mixlstm); ls=x[:4]
__global__ __launch_bounds__(256) void init_xi(
    const float* __restrict__ x, f16* __restrict__ xi2, float* __restrict__ ls)
{
    size_t idx = (size_t)blockIdx.x * 256 + threadIdx.x;
    const size_t total = (size_t)Bsz * Nn * 192;
    if (idx < total) {
        size_t bn = idx / 192;
        int k = (int)(idx - bn * 192);
        if (k < 8) xi2[idx] = (f16)x[bn * 8 + k];
        else if (k >= 136) xi2[idx] = (f16)0.f;
    }
    if (idx < (size_t)Bsz * Nn * 4) {
        size_t bn = idx >> 2;
        ls[idx] = x[bn * 8 + (idx & 3)];
    }
}

// ---------------------------------------------------------------------------
// Init mix: Yhc (B,N,256) f16 = [h-pre | c-pre]; h0 -> xi2[8:136), l2cat[0:128),
// l2cat[128:256); c0 -> c1, c2 (fp32).
// ---------------------------------------------------------------------------
__global__ __launch_bounds__(256) void mix_init(
    const f16* __restrict__ Yhc, const float* __restrict__ G,
    f16* __restrict__ xi2, f16* __restrict__ l2cat,
    float* __restrict__ c1, float* __restrict__ c2)
{
    const int b = blockIdx.x;
    const int tid = threadIdx.x;
    __shared__ float sY[6144], sG[576];
    for (int i = tid; i < 576; i += 256) sG[i] = G[i];
    for (int v = tid; v < 768; v += 256) {
        int c8 = (v & 31) * 8, n = v >> 5;
        f16x8 t = *(const f16x8*)&Yhc[((size_t)b * Nn + n) * 256 + c8];
        float* d = &sY[n * 256 + c8];
#pragma unroll
        for (int u = 0; u < 8; u++) d[u] = (float)t[u];
    }
    __syncthreads();
    for (int w = tid; w < 3072; w += 256) {
        int o = w & 127, m = w >> 7;
        float ah = 0.f, ac = 0.f;
#pragma unroll
        for (int n = 0; n < 24; n++) {
            float g = sG[m * 24 + n];
            ah += g * sY[n * 256 + o];
            ac += g * sY[n * 256 + 128 + o];
        }
        size_t row = (size_t)b * Nn + m;
        f16 hf = (f16)ah;
        xi2[row * 192 + 8 + o] = hf;
        l2cat[row * 256 + o] = hf;
        l2cat[row * 256 + 128 + o] = hf;
        c1[row * 128 + o] = ac;
        c2[row * 128 + o] = ac;
    }
}

// ---------------------------------------------------------------------------
// G-mix + LSTM pointwise. Ypre (B,N,512) f16 pre-mix gates. c fp32 in/out.
// h written f16 to dstA (raw) and dstB (raw or tanh). grid (B, 2 j-tiles).
// ---------------------------------------------------------------------------
__global__ __launch_bounds__(256) void mixlstm(
    const f16* __restrict__ Ypre, const float* __restrict__ G,
    float* __restrict__ c,
    f16* __restrict__ dstA, int strideA,
    f16* __restrict__ dstB, int strideB, int tanhB)
{
    const int b = blockIdx.x;
    const int jt = blockIdx.y * 64;
    const int tid = threadIdx.x;
    __shared__ float sY[6144];   // n, gate, j(64)
    __shared__ float sG[576];
    for (int i = tid; i < 576; i += 256) sG[i] = G[i];
    for (int v = tid; v < 768; v += 256) {
        int j8 = (v & 7) * 8, g = (v >> 3) & 3, n = v >> 5;
        f16x8 t = *(const f16x8*)&Ypre[((size_t)b * Nn + n) * 512 + g * 128 + jt + j8];
        float* d = &sY[n * 256 + g * 64 + j8];
#pragma unroll
        for (int u = 0; u < 8; u++) d[u] = (float)t[u];
    }
    __syncthreads();
    for (int w = tid; w < 1536; w += 256) {
        int j = w & 63, m = w >> 6;
        float gi = 0.f, gf = 0.f, gg = 0.f, go = 0.f;
        const float* gr = &sG[m * 24];
#pragma unroll
        for (int n = 0; n < 24; n++) {
            float g = gr[n];
            gi += g * sY[n * 256 + j];
            gf += g * sY[n * 256 + 64 + j];
            gg += g * sY[n * 256 + 128 + j];
            go += g * sY[n * 256 + 192 + j];
        }
        int col = jt + j;
        size_t row = (size_t)b * Nn + m;
        float cv = c[row * 128 + col];
        float si = 1.f / (1.f + expf(-gi));
        float sf = 1.f / (1.f + expf(-gf));
        float so = 1.f / (1.f + expf(-go));
        float tg = tanhf(gg);
        cv = sf * cv + si * tg;
        c[row * 128 + col] = cv;
        float h = so * tanhf(cv);
        dstA[row * strideA + col] = (f16)h;
        dstB[row * strideB + col] = (f16)(tanhB ? tanhf(h) : h);
    }
}

// ---------------------------------------------------------------------------
// Final per-step: mix fc pre-acts + tanh, head matvecs, second mix, quat,
// outputs, update xi2[0:8) & loc_start. p (B,N,256) f16 = [fc1-pre | fc2-pre].
// ---------------------------------------------------------------------------
__global__ __launch_bounds__(256) void finstep(
    const f16* __restrict__ p, const float* __restrict__ G,
    const float* __restrict__ locW, const float* __restrict__ locb,
    const float* __restrict__ lzW, const float* __restrict__ lzb,
    float* __restrict__ ls, f16* __restrict__ xi2,
    float* __restrict__ out, int t)
{
    const int b = blockIdx.x;
    const int tid = threadIdx.x;
    __shared__ float sP[6144], sY1[3072], sY2[3072];
    __shared__ float sG[576];
    __shared__ float sLp[24][3], sZp[24][4], sL3[24][3], sZ3[24][4];
    for (int i = tid; i < 576; i += 256) sG[i] = G[i];
    for (int v = tid; v < 768; v += 256) {
        int c8 = (v & 31) * 8, n = v >> 5;
        f16x8 tv = *(const f16x8*)&p[((size_t)b * Nn + n) * 256 + c8];
        float* d = &sP[n * 256 + c8];
#pragma unroll
        for (int u = 0; u < 8; u++) d[u] = (float)tv[u];
    }
    __syncthreads();
    for (int w = tid; w < 3072; w += 256) {
        int o = w & 127, m = w >> 7;
        float a1 = 0.f, a2 = 0.f;
#pragma unroll
        for (int n = 0; n < 24; n++) {
            float g = sG[m * 24 + n];
            a1 += g * sP[n * 256 + o];
            a2 += g * sP[n * 256 + 128 + o];
        }
        sY1[w] = tanhf(a1);
        sY2[w] = tanhf(a2);
    }
    __syncthreads();
    if (tid < 72) {
        int m = tid / 3, j = tid - m * 3;
        float s = locb[j];
        for (int o = 0; o < 128; o++) s += sY1[m * 128 + o] * locW[o * 3 + j];
        sLp[m][j] = s;
    } else if (tid < 168) {
        int w2 = tid - 72; int m = w2 >> 2, j = w2 & 3;
        float s = lzb[j];
        for (int o = 0; o < 128; o++) s += sY2[m * 128 + o] * lzW[o * 4 + j];
        sZp[m][j] = s;
    }
    __syncthreads();
    if (tid < 72) {
        int m = tid / 3, j = tid - m * 3;
        float s = 0.f;
#pragma unroll
        for (int n = 0; n < 24; n++) s += sG[m * 24 + n] * sLp[n][j];
        sL3[m][j] = s;
    } else if (tid < 168) {
        int w2 = tid - 72; int m = w2 >> 2, j = w2 & 3;
        float s = 0.f;
#pragma unroll
        for (int n = 0; n < 24; n++) s += sG[m * 24 + n] * sZp[n][j];
        sZ3[m][j] = s;
    }
    __syncthreads();
    if (tid < 24) {
        int m = tid;
        float xx = sL3[m][0], xy = sL3[m][1], xz = sL3[m][2];
        float r = rsqrtf(1.f + xx * xx + xy * xy + xz * xz);
        float dw = r, dx = xx * r, dy = xy * r, dz = xz * r;
        size_t li = ((size_t)b * Nn + m) * 4;
        float qw = ls[li], qx = ls[li + 1], qy = ls[li + 2], qz = ls[li + 3];
        float lw = qw * dw - qx * dx - qy * dy - qz * dz;
        float lx = qw * dx + qx * dw + qy * dz - qz * dy;
        float ly = qw * dy - qx * dz + qy * dw + qz * dx;
        float lz = qw * dz + qx * dy - qy * dx + qz * dw;
        size_t oi = (((size_t)b * Tt + t) * Nn + m) * 4;
        out[oi + 0] = lw; out[oi + 1] = lx; out[oi + 2] = ly; out[oi + 3] = lz;
        size_t zi = (size_t)Bsz * Tt * Nn * 4 + oi;
        out[zi + 0] = sZ3[m][0]; out[zi + 1] = sZ3[m][1];
        out[zi + 2] = sZ3[m][2]; out[zi + 3] = sZ3[m][3];
        ls[li] = lw; ls[li + 1] = lx; ls[li + 2] = ly; ls[li + 3] = lz;
        size_t xb = ((size_t)b * Nn + m) * 192;
        xi2[xb + 0] = (f16)lw; xi2[xb + 1] = (f16)lx; xi2[xb + 2] = (f16)ly; xi2[xb + 3] = (f16)lz;
        xi2[xb + 4] = (f16)dw; xi2[xb + 5] = (f16)dx; xi2[xb + 6] = (f16)dy; xi2[xb + 7] = (f16)dz;
    }
}

extern "C" void kernel_launch(void* const* d_in, const int* in_sizes, int n_in,
                              void* d_out, int out_size, void* d_ws, size_t ws_size,
                              hipStream_t stream)
{
    const float* x    = (const float*)d_in[0];
    const float* enc  = (const float*)d_in[1];
    const float* z    = (const float*)d_in[2];
    const float* G    = (const float*)d_in[4];
    const float* Wx0  = (const float*)d_in[5];
    const float* Wh0  = (const float*)d_in[6];
    const float* b0i  = (const float*)d_in[7];
    const float* Wx1  = (const float*)d_in[8];
    const float* Wh1  = (const float*)d_in[9];
    const float* b1i  = (const float*)d_in[10];
    const float* fcW  = (const float*)d_in[11];
    const float* fcb  = (const float*)d_in[12];
    const float* fc2W = (const float*)d_in[13];
    const float* fc2b = (const float*)d_in[14];
    const float* ih1W = (const float*)d_in[15];
    const float* ih1b = (const float*)d_in[16];
    const float* ih2W = (const float*)d_in[17];
    const float* ih2b = (const float*)d_in[18];
    const float* locW = (const float*)d_in[19];
    const float* locb = (const float*)d_in[20];
    const float* lzW  = (const float*)d_in[21];
    const float* lzb  = (const float*)d_in[22];
    float* out = (float*)d_out;

    const size_t BN = (size_t)Bsz * Nn;
    char* wp = (char*)d_ws;
    size_t off = 0;
    auto carve = [&](size_t bytes) -> char* {
        char* pc = wp + off;
        off += (bytes + 255) & ~(size_t)255;
        return pc;
    };
    f16*   Wz     = (f16*)carve((size_t)Nn * 512 * 64 * 2);
    f16*   Wt0    = (f16*)carve((size_t)Nn * 512 * 192 * 2);
    f16*   Wt1    = (f16*)carve((size_t)Nn * 512 * 256 * 2);
    f16*   Wtf    = (f16*)carve((size_t)Nn * 256 * 128 * 2);
    f16*   Wti    = (f16*)carve((size_t)256 * 256 * 2);
    float* bcat   = (float*)carve((size_t)Nn * 256 * 4);
    float* bi     = (float*)carve(256 * 4);
    f16*   base1  = (f16*)carve(BN * 512 * 2);
    f16*   xi2    = (f16*)carve(BN * 192 * 2);
    f16*   l2cat  = (f16*)carve(BN * 256 * 2);
    f16*   yib    = (f16*)carve(BN * 128 * 2);
    float* c1     = (float*)carve(BN * 128 * 4);
    float* c2     = (float*)carve(BN * 128 * 4);
    float* ls     = (float*)carve(BN * 4 * 4);
    f16*   yp     = (f16*)carve(BN * 512 * 2);
    f16*   pbuf   = (f16*)carve(BN * 256 * 2);

    // ---- one-time prep ----
    prep_w01<<<24576, 256, 0, stream>>>(Wx0, Wh0, Wx1, Wh1, Wz, Wt0, Wt1);
    prep_wf<<<3072, 256, 0, stream>>>(fcW, fc2W, Wtf);
    prep_wi<<<256, 256, 0, stream>>>(ih1W, ih2W, ih1b, ih2b, fcb, fc2b, Wti, bi, bcat);
    init_xi<<<9216, 256, 0, stream>>>(x, xi2, ls);

    // base1 = z . Wx0[:,:64,:] + b0    (constant over all T steps)
    gemm_mfma<2, 4><<<dim3(8, 4, 24), 256, 0, stream>>>(
        nullptr, z, 64, Wz, (size_t)512 * 64, b0i, 512, nullptr, base1, 512);
    // init states: [h0|c0] from enc
    gemm_mfma<2, 4><<<dim3(4, 4, 24), 256, 0, stream>>>(
        nullptr, enc, 256, Wti, 0, bi, 0, nullptr, yp, 256);
    mix_init<<<512, 256, 0, stream>>>(yp, G, xi2, l2cat, c1, c2);

    // ---- T sequential steps ----
    for (int t = 0; t < Tt; t++) {
        gemm_mfma<2, 4><<<dim3(8, 4, 24), 256, 0, stream>>>(
            xi2, nullptr, 192, Wt0, (size_t)512 * 192, nullptr, 0, base1, yp, 512);
        mixlstm<<<dim3(512, 2), 256, 0, stream>>>(yp, G, c1, xi2 + 8, 192, l2cat, 256, 0);
        gemm_mfma<2, 4><<<dim3(8, 4, 24), 256, 0, stream>>>(
            l2cat, nullptr, 256, Wt1, (size_t)512 * 256, b1i, 512, nullptr, yp, 512);
        mixlstm<<<dim3(512, 2), 256, 0, stream>>>(yp, G, c2, l2cat + 128, 256, yib, 128, 1);
        gemm_mfma<2, 4><<<dim3(4, 4, 24), 256, 0, stream>>>(
            yib, nullptr, 128, Wtf, (size_t)256 * 128, bcat, 256, nullptr, pbuf, 256);
        finstep<<<512, 256, 0, stream>>>(pbuf, G, locW, locb, lzW, lzb, ls, xi2, out, t);
    }
}

// Round 9
// 2339.857 us; speedup vs baseline: 1.3603x; 1.0051x over previous
//
#include <hip/hip_runtime.h>
#include <math.h>

#define Bsz 512
#define Nn  24
#define Tt  25
// IN=8, L=64, H=256, OUT=128
// layer1: per-step K = 8(loc,locd) + 128(h1) -> padded 192; z-part hoisted to base1
// layer2: K=256; fc: K=128; init: K=256 from enc (fp32)

typedef _Float16 f16;
typedef _Float16 f16x8 __attribute__((ext_vector_type(8)));
typedef _Float16 f16x4 __attribute__((ext_vector_type(4)));
typedef float f32x4 __attribute__((ext_vector_type(4)));

// ---------------------------------------------------------------------------
// MFMA fp16 GEMM, per-node block-diagonal, W-as-A orientation (R4 structure):
//   Y[b,n,o] = sum_k Act[b,n,k] * W[n,o,k] + bias[n,o] (+ base16[b,n,o])
// Register-prefetch pipelined K-loop. R9 change: KA and OO are template
// constants -> k-loop fully unrolls into straight-line pipelined code,
// branch eliminated, offsets fold to immediates. Arithmetic order identical.
// ---------------------------------------------------------------------------
template <int FM, int FN, int KA, int OO>
__global__ __launch_bounds__(256) void gemm_mfma(
    const f16* __restrict__ Act, const float* __restrict__ Act32,
    const f16* __restrict__ W, size_t wstride,
    const float* __restrict__ bias, int bstride,
    const f16* __restrict__ base16,
    f16* __restrict__ Y)
{
    const int BM = FM * 32, BN = FN * 32;
    const int n  = blockIdx.z;
    const int o0 = blockIdx.x * BM;
    const int b0 = blockIdx.y * BN;
    const int tid  = threadIdx.x;
    const int wave = tid >> 6, lane = tid & 63;
    const int wm = (wave >> 1) * FM * 16;   // o offset of wave
    const int wn = (wave & 1) * FN * 16;    // b offset of wave
    const int m16 = lane & 15, quad = lane >> 4;

    __shared__ __attribute__((aligned(16))) f16 sW[BM][72];  // o-rows, k-cols (+pad)
    __shared__ __attribute__((aligned(16))) f16 sB[BN][72];  // b-rows, k-cols

    const f16* Wn = W + (size_t)n * wstride;
    f32x4 acc[FM][FN] = {};

    const int r  = tid >> 3;        // staging row 0..31
    const int cc = (tid & 7) * 8;   // staging col (halfs)
    constexpr int nk = KA / 64;     // 64-wide k tiles (compile-time)

    f16x8 rW[FM], rB[FN];
    float rBf[FN][8];

    // ---- prefetch k-tile 0 into registers ----
#pragma unroll
    for (int i = 0; i < FM; i++)
        rW[i] = *(const f16x8*)&Wn[(size_t)(o0 + r + 32 * i) * KA + cc];
    if (Act) {
#pragma unroll
        for (int j = 0; j < FN; j++)
            rB[j] = *(const f16x8*)&Act[((size_t)(b0 + r + 32 * j) * Nn + n) * KA + cc];
    } else {
#pragma unroll
        for (int j = 0; j < FN; j++) {
            const float* src = &Act32[((size_t)(b0 + r + 32 * j) * Nn + n) * KA + cc];
#pragma unroll
            for (int u = 0; u < 8; u++) rBf[j][u] = src[u];
        }
    }

#pragma unroll
    for (int it = 0; it < nk; it++) {
        // ---- commit prefetched tile to LDS ----
#pragma unroll
        for (int i = 0; i < FM; i++)
            *(f16x8*)&sW[r + 32 * i][cc] = rW[i];
        if (Act) {
#pragma unroll
            for (int j = 0; j < FN; j++)
                *(f16x8*)&sB[r + 32 * j][cc] = rB[j];
        } else {
#pragma unroll
            for (int j = 0; j < FN; j++) {
                f16x8 v;
#pragma unroll
                for (int u = 0; u < 8; u++) v[u] = (f16)rBf[j][u];
                *(f16x8*)&sB[r + 32 * j][cc] = v;
            }
        }
        __syncthreads();

        // ---- issue next tile's global loads (latency hides under MFMA) ----
        if (it + 1 < nk) {
            const int k0n = (it + 1) * 64;
#pragma unroll
            for (int i = 0; i < FM; i++)
                rW[i] = *(const f16x8*)&Wn[(size_t)(o0 + r + 32 * i) * KA + k0n + cc];
            if (Act) {
#pragma unroll
                for (int j = 0; j < FN; j++)
                    rB[j] = *(const f16x8*)&Act[((size_t)(b0 + r + 32 * j) * Nn + n) * KA + k0n + cc];
            } else {
#pragma unroll
                for (int j = 0; j < FN; j++) {
                    const float* src = &Act32[((size_t)(b0 + r + 32 * j) * Nn + n) * KA + k0n + cc];
#pragma unroll
                    for (int u = 0; u < 8; u++) rBf[j][u] = src[u];
                }
            }
        }

        // ---- MFMA on the committed LDS tile ----
#pragma unroll
        for (int kk = 0; kk < 64; kk += 32) {
            f16x8 af[FM], bf[FN];
#pragma unroll
            for (int i = 0; i < FM; i++)
                af[i] = *(const f16x8*)&sW[wm + i * 16 + m16][kk + quad * 8];
#pragma unroll
            for (int j = 0; j < FN; j++)
                bf[j] = *(const f16x8*)&sB[wn + j * 16 + m16][kk + quad * 8];
#pragma unroll
            for (int i = 0; i < FM; i++)
#pragma unroll
                for (int j = 0; j < FN; j++)
                    acc[i][j] = __builtin_amdgcn_mfma_f32_16x16x32_f16(af[i], bf[j], acc[i][j], 0, 0, 0);
        }
        __syncthreads();
    }
    // epilogue: D[row=o][col=b]; per lane, regs = 4 consecutive o at quad*4
#pragma unroll
    for (int i = 0; i < FM; i++) {
        const int orow = o0 + wm + i * 16 + quad * 4;
        float4 bv = make_float4(0.f, 0.f, 0.f, 0.f);
        if (bias) bv = *(const float4*)&bias[(size_t)n * bstride + orow];
#pragma unroll
        for (int j = 0; j < FN; j++) {
            const int bcol = b0 + wn + j * 16 + m16;
            size_t yi = ((size_t)bcol * Nn + n) * (size_t)OO + orow;
            float v0 = acc[i][j][0] + bv.x;
            float v1 = acc[i][j][1] + bv.y;
            float v2 = acc[i][j][2] + bv.z;
            float v3 = acc[i][j][3] + bv.w;
            if (base16) {
                f16x4 bb = *(const f16x4*)&base16[yi];
                v0 += (float)bb[0]; v1 += (float)bb[1];
                v2 += (float)bb[2]; v3 += (float)bb[3];
            }
            f16x4 o4; o4[0] = (f16)v0; o4[1] = (f16)v1; o4[2] = (f16)v2; o4[3] = (f16)v3;
            *(f16x4*)&Y[yi] = o4;
        }
    }
}

// ---------------------------------------------------------------------------
// Weight prep: Wz (24,512,64)=Wx0[:, :64, :]^T; Wt0 (24,512,192)=[Wx0[64:72]|Wh0|0]^T;
// Wt1 (24,512,256)=[Wx1|Wh1]^T
// ---------------------------------------------------------------------------
__global__ __launch_bounds__(256) void prep_w01(
    const float* __restrict__ Wx0, const float* __restrict__ Wh0,
    const float* __restrict__ Wx1, const float* __restrict__ Wh1,
    f16* __restrict__ Wz, f16* __restrict__ Wt0, f16* __restrict__ Wt1)
{
    size_t idx = (size_t)blockIdx.x * 256 + threadIdx.x;
    const size_t nz = (size_t)Nn * 512 * 64;       // 786432
    const size_t n0 = (size_t)Nn * 512 * 192;      // 2359296
    const size_t n1 = (size_t)Nn * 512 * 256;      // 3145728
    if (idx < nz) {
        int k = idx & 63; int o = (idx >> 6) & 511; int n = (int)(idx >> 15);
        Wz[idx] = (f16)Wx0[((size_t)n * 72 + k) * 512 + o];
    } else if (idx < nz + n0) {
        size_t i2 = idx - nz;
        int k = (int)(i2 % 192);
        size_t no = i2 / 192;
        int o = (int)(no & 511); int n = (int)(no >> 9);
        float v = 0.f;
        if (k < 8) v = Wx0[((size_t)n * 72 + 64 + k) * 512 + o];
        else if (k < 136) v = Wh0[((size_t)n * 128 + (k - 8)) * 512 + o];
        Wt0[i2] = (f16)v;
    } else if (idx < nz + n0 + n1) {
        size_t i3 = idx - nz - n0;
        int k = (int)(i3 & 255);
        size_t no = i3 >> 8;
        int o = (int)(no & 511); int n = (int)(no >> 9);
        float v = (k < 128) ? Wx1[((size_t)n * 128 + k) * 512 + o]
                            : Wh1[((size_t)n * 128 + (k - 128)) * 512 + o];
        Wt1[i3] = (f16)v;
    }
}

// Wtf (24,256,128): o<128 -> fcW^T, else fc2W^T
__global__ __launch_bounds__(256) void prep_wf(
    const float* __restrict__ fcW, const float* __restrict__ fc2W,
    f16* __restrict__ Wtf)
{
    size_t idx = (size_t)blockIdx.x * 256 + threadIdx.x;
    if (idx >= (size_t)Nn * 256 * 128) return;
    int k = (int)(idx & 127);
    size_t no = idx >> 7;
    int o = (int)(no & 255); int n = (int)(no >> 8);
    float v = (o < 128) ? fcW[((size_t)n * 128 + k) * 128 + o]
                        : fc2W[((size_t)n * 128 + k) * 128 + (o - 128)];
    Wtf[idx] = (f16)v;
}

// Wti (256,256) = [ih1W | ih2W]^T ; bi (256) ; bcat (24,256)
__global__ __launch_bounds__(256) void prep_wi(
    const float* __restrict__ ih1W, const float* __restrict__ ih2W,
    const float* __restrict__ ih1b, const float* __restrict__ ih2b,
    const float* __restrict__ fcb, const float* __restrict__ fc2b,
    f16* __restrict__ Wti, float* __restrict__ bi, float* __restrict__ bcat)
{
    int idx = blockIdx.x * 256 + threadIdx.x;   // 65536
    int k = idx & 255, o = idx >> 8;
    Wti[idx] = (f16)((o < 128) ? ih1W[(size_t)k * 128 + o] : ih2W[(size_t)k * 128 + (o - 128)]);
    if (idx < 256) bi[idx] = (idx < 128) ? ih1b[idx] : ih2b[idx - 128];
    if (idx < Nn * 256) {
        int n = idx >> 8, oo = idx & 255;
        bcat[idx] = (oo < 128) ? fcb[n * 128 + oo] : fc2b[n * 128 + (oo - 128)];
    }
}

// xi2[b,n,0:8)=x, [136:192)=0 ([8:136) = h1, filled by mix_init/mixlstm); ls=x[:4]
__global__ __launch_bounds__(256) void init_xi(
    const float* __restrict__ x, f16* __restrict__ xi2, float* __restrict__ ls)
{
    size_t idx = (size_t)blockIdx.x * 256 + threadIdx.x;
    const size_t total = (size_t)Bsz * Nn * 192;
    if (idx < total) {
        size_t bn = idx / 192;
        int k = (int)(idx - bn * 192);
        if (k < 8) xi2[idx] = (f16)x[bn * 8 + k];
        else if (k >= 136) xi2[idx] = (f16)0.f;
    }
    if (idx < (size_t)Bsz * Nn * 4) {
        size_t bn = idx >> 2;
        ls[idx] = x[bn * 8 + (idx & 3)];
    }
}

// ---------------------------------------------------------------------------
// Init mix: Yhc (B,N,256) f16 = [h-pre | c-pre]; h0 -> xi2[8:136), l2cat[0:128),
// l2cat[128:256); c0 -> c1, c2 (fp32).
// ---------------------------------------------------------------------------
__global__ __launch_bounds__(256) void mix_init(
    const f16* __restrict__ Yhc, const float* __restrict__ G,
    f16* __restrict__ xi2, f16* __restrict__ l2cat,
    float* __restrict__ c1, float* __restrict__ c2)
{
    const int b = blockIdx.x;
    const int tid = threadIdx.x;
    __shared__ float sY[6144], sG[576];
    for (int i = tid; i < 576; i += 256) sG[i] = G[i];
    for (int v = tid; v < 768; v += 256) {
        int c8 = (v & 31) * 8, n = v >> 5;
        f16x8 t = *(const f16x8*)&Yhc[((size_t)b * Nn + n) * 256 + c8];
        float* d = &sY[n * 256 + c8];
#pragma unroll
        for (int u = 0; u < 8; u++) d[u] = (float)t[u];
    }
    __syncthreads();
    for (int w = tid; w < 3072; w += 256) {
        int o = w & 127, m = w >> 7;
        float ah = 0.f, ac = 0.f;
#pragma unroll
        for (int n = 0; n < 24; n++) {
            float g = sG[m * 24 + n];
            ah += g * sY[n * 256 + o];
            ac += g * sY[n * 256 + 128 + o];
        }
        size_t row = (size_t)b * Nn + m;
        f16 hf = (f16)ah;
        xi2[row * 192 + 8 + o] = hf;
        l2cat[row * 256 + o] = hf;
        l2cat[row * 256 + 128 + o] = hf;
        c1[row * 128 + o] = ac;
        c2[row * 128 + o] = ac;
    }
}

// ---------------------------------------------------------------------------
// G-mix + LSTM pointwise. Ypre (B,N,512) f16 pre-mix gates. c fp32 in/out.
// h written f16 to dstA (raw) and dstB (raw or tanh). grid (B, 2 j-tiles).
// ---------------------------------------------------------------------------
__global__ __launch_bounds__(256) void mixlstm(
    const f16* __restrict__ Ypre, const float* __restrict__ G,
    float* __restrict__ c,
    f16* __restrict__ dstA, int strideA,
    f16* __restrict__ dstB, int strideB, int tanhB)
{
    const int b = blockIdx.x;
    const int jt = blockIdx.y * 64;
    const int tid = threadIdx.x;
    __shared__ float sY[6144];   // n, gate, j(64)
    __shared__ float sG[576];
    for (int i = tid; i < 576; i += 256) sG[i] = G[i];
    for (int v = tid; v < 768; v += 256) {
        int j8 = (v & 7) * 8, g = (v >> 3) & 3, n = v >> 5;
        f16x8 t = *(const f16x8*)&Ypre[((size_t)b * Nn + n) * 512 + g * 128 + jt + j8];
        float* d = &sY[n * 256 + g * 64 + j8];
#pragma unroll
        for (int u = 0; u < 8; u++) d[u] = (float)t[u];
    }
    __syncthreads();
    for (int w = tid; w < 1536; w += 256) {
        int j = w & 63, m = w >> 6;
        float gi = 0.f, gf = 0.f, gg = 0.f, go = 0.f;
        const float* gr = &sG[m * 24];
#pragma unroll
        for (int n = 0; n < 24; n++) {
            float g = gr[n];
            gi += g * sY[n * 256 + j];
            gf += g * sY[n * 256 + 64 + j];
            gg += g * sY[n * 256 + 128 + j];
            go += g * sY[n * 256 + 192 + j];
        }
        int col = jt + j;
        size_t row = (size_t)b * Nn + m;
        float cv = c[row * 128 + col];
        float si = 1.f / (1.f + expf(-gi));
        float sf = 1.f / (1.f + expf(-gf));
        float so = 1.f / (1.f + expf(-go));
        float tg = tanhf(gg);
        cv = sf * cv + si * tg;
        c[row * 128 + col] = cv;
        float h = so * tanhf(cv);
        dstA[row * strideA + col] = (f16)h;
        dstB[row * strideB + col] = (f16)(tanhB ? tanhf(h) : h);
    }
}

// ---------------------------------------------------------------------------
// Final per-step: mix fc pre-acts + tanh, head matvecs, second mix, quat,
// outputs, update xi2[0:8) & loc_start. p (B,N,256) f16 = [fc1-pre | fc2-pre].
// ---------------------------------------------------------------------------
__global__ __launch_bounds__(256) void finstep(
    const f16* __restrict__ p, const float* __restrict__ G,
    const float* __restrict__ locW, const float* __restrict__ locb,
    const float* __restrict__ lzW, const float* __restrict__ lzb,
    float* __restrict__ ls, f16* __restrict__ xi2,
    float* __restrict__ out, int t)
{
    const int b = blockIdx.x;
    const int tid = threadIdx.x;
    __shared__ float sP[6144], sY1[3072], sY2[3072];
    __shared__ float sG[576];
    __shared__ float sLp[24][3], sZp[24][4], sL3[24][3], sZ3[24][4];
    for (int i = tid; i < 576; i += 256) sG[i] = G[i];
    for (int v = tid; v < 768; v += 256) {
        int c8 = (v & 31) * 8, n = v >> 5;
        f16x8 tv = *(const f16x8*)&p[((size_t)b * Nn + n) * 256 + c8];
        float* d = &sP[n * 256 + c8];
#pragma unroll
        for (int u = 0; u < 8; u++) d[u] = (float)tv[u];
    }
    __syncthreads();
    for (int w = tid; w < 3072; w += 256) {
        int o = w & 127, m = w >> 7;
        float a1 = 0.f, a2 = 0.f;
#pragma unroll
        for (int n = 0; n < 24; n++) {
            float g = sG[m * 24 + n];
            a1 += g * sP[n * 256 + o];
            a2 += g * sP[n * 256 + 128 + o];
        }
        sY1[w] = tanhf(a1);
        sY2[w] = tanhf(a2);
    }
    __syncthreads();
    if (tid < 72) {
        int m = tid / 3, j = tid - m * 3;
        float s = locb[j];
        for (int o = 0; o < 128; o++) s += sY1[m * 128 + o] * locW[o * 3 + j];
        sLp[m][j] = s;
    } else if (tid < 168) {
        int w2 = tid - 72; int m = w2 >> 2, j = w2 & 3;
        float s = lzb[j];
        for (int o = 0; o < 128; o++) s += sY2[m * 128 + o] * lzW[o * 4 + j];
        sZp[m][j] = s;
    }
    __syncthreads();
    if (tid < 72) {
        int m = tid / 3, j = tid - m * 3;
        float s = 0.f;
#pragma unroll
        for (int n = 0; n < 24; n++) s += sG[m * 24 + n] * sLp[n][j];
        sL3[m][j] = s;
    } else if (tid < 168) {
        int w2 = tid - 72; int m = w2 >> 2, j = w2 & 3;
        float s = 0.f;
#pragma unroll
        for (int n = 0; n < 24; n++) s += sG[m * 24 + n] * sZp[n][j];
        sZ3[m][j] = s;
    }
    __syncthreads();
    if (tid < 24) {
        int m = tid;
        float xx = sL3[m][0], xy = sL3[m][1], xz = sL3[m][2];
        float r = rsqrtf(1.f + xx * xx + xy * xy + xz * xz);
        float dw = r, dx = xx * r, dy = xy * r, dz = xz * r;
        size_t li = ((size_t)b * Nn + m) * 4;
        float qw = ls[li], qx = ls[li + 1], qy = ls[li + 2], qz = ls[li + 3];
        float lw = qw * dw - qx * dx - qy * dy - qz * dz;
        float lx = qw * dx + qx * dw + qy * dz - qz * dy;
        float ly = qw * dy - qx * dz + qy * dw + qz * dx;
        float lz = qw * dz + qx * dy - qy * dx + qz * dw;
        size_t oi = (((size_t)b * Tt + t) * Nn + m) * 4;
        out[oi + 0] = lw; out[oi + 1] = lx; out[oi + 2] = ly; out[oi + 3] = lz;
        size_t zi = (size_t)Bsz * Tt * Nn * 4 + oi;
        out[zi + 0] = sZ3[m][0]; out[zi + 1] = sZ3[m][1];
        out[zi + 2] = sZ3[m][2]; out[zi + 3] = sZ3[m][3];
        ls[li] = lw; ls[li + 1] = lx; ls[li + 2] = ly; ls[li + 3] = lz;
        size_t xb = ((size_t)b * Nn + m) * 192;
        xi2[xb + 0] = (f16)lw; xi2[xb + 1] = (f16)lx; xi2[xb + 2] = (f16)ly; xi2[xb + 3] = (f16)lz;
        xi2[xb + 4] = (f16)dw; xi2[xb + 5] = (f16)dx; xi2[xb + 6] = (f16)dy; xi2[xb + 7] = (f16)dz;
    }
}

extern "C" void kernel_launch(void* const* d_in, const int* in_sizes, int n_in,
                              void* d_out, int out_size, void* d_ws, size_t ws_size,
                              hipStream_t stream)
{
    const float* x    = (const float*)d_in[0];
    const float* enc  = (const float*)d_in[1];
    const float* z    = (const float*)d_in[2];
    const float* G    = (const float*)d_in[4];
    const float* Wx0  = (const float*)d_in[5];
    const float* Wh0  = (const float*)d_in[6];
    const float* b0i  = (const float*)d_in[7];
    const float* Wx1  = (const float*)d_in[8];
    const float* Wh1  = (const float*)d_in[9];
    const float* b1i  = (const float*)d_in[10];
    const float* fcW  = (const float*)d_in[11];
    const float* fcb  = (const float*)d_in[12];
    const float* fc2W = (const float*)d_in[13];
    const float* fc2b = (const float*)d_in[14];
    const float* ih1W = (const float*)d_in[15];
    const float* ih1b = (const float*)d_in[16];
    const float* ih2W = (const float*)d_in[17];
    const float* ih2b = (const float*)d_in[18];
    const float* locW = (const float*)d_in[19];
    const float* locb = (const float*)d_in[20];
    const float* lzW  = (const float*)d_in[21];
    const float* lzb  = (const float*)d_in[22];
    float* out = (float*)d_out;

    const size_t BN = (size_t)Bsz * Nn;
    char* wp = (char*)d_ws;
    size_t off = 0;
    auto carve = [&](size_t bytes) -> char* {
        char* pc = wp + off;
        off += (bytes + 255) & ~(size_t)255;
        return pc;
    };
    f16*   Wz     = (f16*)carve((size_t)Nn * 512 * 64 * 2);
    f16*   Wt0    = (f16*)carve((size_t)Nn * 512 * 192 * 2);
    f16*   Wt1    = (f16*)carve((size_t)Nn * 512 * 256 * 2);
    f16*   Wtf    = (f16*)carve((size_t)Nn * 256 * 128 * 2);
    f16*   Wti    = (f16*)carve((size_t)256 * 256 * 2);
    float* bcat   = (float*)carve((size_t)Nn * 256 * 4);
    float* bi     = (float*)carve(256 * 4);
    f16*   base1  = (f16*)carve(BN * 512 * 2);
    f16*   xi2    = (f16*)carve(BN * 192 * 2);
    f16*   l2cat  = (f16*)carve(BN * 256 * 2);
    f16*   yib    = (f16*)carve(BN * 128 * 2);
    float* c1     = (float*)carve(BN * 128 * 4);
    float* c2     = (float*)carve(BN * 128 * 4);
    float* ls     = (float*)carve(BN * 4 * 4);
    f16*   yp     = (f16*)carve(BN * 512 * 2);
    f16*   pbuf   = (f16*)carve(BN * 256 * 2);

    // ---- one-time prep ----
    prep_w01<<<24576, 256, 0, stream>>>(Wx0, Wh0, Wx1, Wh1, Wz, Wt0, Wt1);
    prep_wf<<<3072, 256, 0, stream>>>(fcW, fc2W, Wtf);
    prep_wi<<<256, 256, 0, stream>>>(ih1W, ih2W, ih1b, ih2b, fcb, fc2b, Wti, bi, bcat);
    init_xi<<<9216, 256, 0, stream>>>(x, xi2, ls);

    // base1 = z . Wx0[:,:64,:] + b0    (constant over all T steps)
    gemm_mfma<2, 4, 64, 512><<<dim3(8, 4, 24), 256, 0, stream>>>(
        nullptr, z, Wz, (size_t)512 * 64, b0i, 512, nullptr, base1);
    // init states: [h0|c0] from enc
    gemm_mfma<2, 4, 256, 256><<<dim3(4, 4, 24), 256, 0, stream>>>(
        nullptr, enc, Wti, 0, bi, 0, nullptr, yp);
    mix_init<<<512, 256, 0, stream>>>(yp, G, xi2, l2cat, c1, c2);

    // ---- T sequential steps ----
    for (int t = 0; t < Tt; t++) {
        gemm_mfma<2, 4, 192, 512><<<dim3(8, 4, 24), 256, 0, stream>>>(
            xi2, nullptr, Wt0, (size_t)512 * 192, nullptr, 0, base1, yp);
        mixlstm<<<dim3(512, 2), 256, 0, stream>>>(yp, G, c1, xi2 + 8, 192, l2cat, 256, 0);
        gemm_mfma<2, 4, 256, 512><<<dim3(8, 4, 24), 256, 0, stream>>>(
            l2cat, nullptr, Wt1, (size_t)512 * 256, b1i, 512, nullptr, yp);
        mixlstm<<<dim3(512, 2), 256, 0, stream>>>(yp, G, c2, l2cat + 128, 256, yib, 128, 1);
        gemm_mfma<2, 4, 128, 256><<<dim3(4, 4, 24), 256, 0, stream>>>(
            yib, nullptr, Wtf, (size_t)256 * 128, bcat, 256, nullptr, pbuf);
        finstep<<<512, 256, 0, stream>>>(pbuf, G, locW, locb, lzW, lzb, ls, xi2, out, t);
    }
}

// Round 10
// 2334.539 us; speedup vs baseline: 1.3634x; 1.0023x over previous
//
#include <hip/hip_runtime.h>
#include <math.h>

#define Bsz 512
#define Nn  24
#define Tt  25
// IN=8, L=64, H=256, OUT=128
// layer1: per-step K = 8(loc,locd) + 128(h1) = 136 real, padded 192; z-part in base1
// layer2: K=256; fc: K=128; init: K=256 from enc (fp32)

typedef _Float16 f16;
typedef _Float16 f16x8 __attribute__((ext_vector_type(8)));
typedef _Float16 f16x4 __attribute__((ext_vector_type(4)));
typedef float f32x4 __attribute__((ext_vector_type(4)));

// ---------------------------------------------------------------------------
// MFMA fp16 GEMM, per-node block-diagonal, W-as-A orientation (R9 structure):
//   Y[b,n,o] = sum_k Act[b,n,k] * W[n,o,k] + bias[n,o] (+ base16[b,n,o])
// KA/OO compile-time; k-loop fully unrolled. R10 change: KREAL marks the real
// K extent — kk half-tiles entirely in the zero-pad region (it*64+kk >= KREAL)
// are skipped at COMPILE TIME. Skipped blocks contributed exact zeros (both
// operands zero-filled there), so results are bit-identical.
// ---------------------------------------------------------------------------
template <int FM, int FN, int KA, int OO, int KREAL = KA>
__global__ __launch_bounds__(256) void gemm_mfma(
    const f16* __restrict__ Act, const float* __restrict__ Act32,
    const f16* __restrict__ W, size_t wstride,
    const float* __restrict__ bias, int bstride,
    const f16* __restrict__ base16,
    f16* __restrict__ Y)
{
    const int BM = FM * 32, BN = FN * 32;
    const int n  = blockIdx.z;
    const int o0 = blockIdx.x * BM;
    const int b0 = blockIdx.y * BN;
    const int tid  = threadIdx.x;
    const int wave = tid >> 6, lane = tid & 63;
    const int wm = (wave >> 1) * FM * 16;   // o offset of wave
    const int wn = (wave & 1) * FN * 16;    // b offset of wave
    const int m16 = lane & 15, quad = lane >> 4;

    __shared__ __attribute__((aligned(16))) f16 sW[BM][72];  // o-rows, k-cols (+pad)
    __shared__ __attribute__((aligned(16))) f16 sB[BN][72];  // b-rows, k-cols

    const f16* Wn = W + (size_t)n * wstride;
    f32x4 acc[FM][FN] = {};

    const int r  = tid >> 3;        // staging row 0..31
    const int cc = (tid & 7) * 8;   // staging col (halfs)
    constexpr int nk = KA / 64;     // 64-wide k tiles (compile-time)

    f16x8 rW[FM], rB[FN];
    float rBf[FN][8];

    // ---- prefetch k-tile 0 into registers ----
#pragma unroll
    for (int i = 0; i < FM; i++)
        rW[i] = *(const f16x8*)&Wn[(size_t)(o0 + r + 32 * i) * KA + cc];
    if (Act) {
#pragma unroll
        for (int j = 0; j < FN; j++)
            rB[j] = *(const f16x8*)&Act[((size_t)(b0 + r + 32 * j) * Nn + n) * KA + cc];
    } else {
#pragma unroll
        for (int j = 0; j < FN; j++) {
            const float* src = &Act32[((size_t)(b0 + r + 32 * j) * Nn + n) * KA + cc];
#pragma unroll
            for (int u = 0; u < 8; u++) rBf[j][u] = src[u];
        }
    }

#pragma unroll
    for (int it = 0; it < nk; it++) {
        // ---- commit prefetched tile to LDS ----
#pragma unroll
        for (int i = 0; i < FM; i++)
            *(f16x8*)&sW[r + 32 * i][cc] = rW[i];
        if (Act) {
#pragma unroll
            for (int j = 0; j < FN; j++)
                *(f16x8*)&sB[r + 32 * j][cc] = rB[j];
        } else {
#pragma unroll
            for (int j = 0; j < FN; j++) {
                f16x8 v;
#pragma unroll
                for (int u = 0; u < 8; u++) v[u] = (f16)rBf[j][u];
                *(f16x8*)&sB[r + 32 * j][cc] = v;
            }
        }
        __syncthreads();

        // ---- issue next tile's global loads (latency hides under MFMA) ----
        if (it + 1 < nk) {
            const int k0n = (it + 1) * 64;
#pragma unroll
            for (int i = 0; i < FM; i++)
                rW[i] = *(const f16x8*)&Wn[(size_t)(o0 + r + 32 * i) * KA + k0n + cc];
            if (Act) {
#pragma unroll
                for (int j = 0; j < FN; j++)
                    rB[j] = *(const f16x8*)&Act[((size_t)(b0 + r + 32 * j) * Nn + n) * KA + k0n + cc];
            } else {
#pragma unroll
                for (int j = 0; j < FN; j++) {
                    const float* src = &Act32[((size_t)(b0 + r + 32 * j) * Nn + n) * KA + k0n + cc];
#pragma unroll
                    for (int u = 0; u < 8; u++) rBf[j][u] = src[u];
                }
            }
        }

        // ---- MFMA on the committed LDS tile (skip all-zero-pad half-tiles) ----
#pragma unroll
        for (int kk = 0; kk < 64; kk += 32) {
            if (it * 64 + kk < KREAL) {
                f16x8 af[FM], bf[FN];
#pragma unroll
                for (int i = 0; i < FM; i++)
                    af[i] = *(const f16x8*)&sW[wm + i * 16 + m16][kk + quad * 8];
#pragma unroll
                for (int j = 0; j < FN; j++)
                    bf[j] = *(const f16x8*)&sB[wn + j * 16 + m16][kk + quad * 8];
#pragma unroll
                for (int i = 0; i < FM; i++)
#pragma unroll
                    for (int j = 0; j < FN; j++)
                        acc[i][j] = __builtin_amdgcn_mfma_f32_16x16x32_f16(af[i], bf[j], acc[i][j], 0, 0, 0);
            }
        }
        __syncthreads();
    }
    // epilogue: D[row=o][col=b]; per lane, regs = 4 consecutive o at quad*4
#pragma unroll
    for (int i = 0; i < FM; i++) {
        const int orow = o0 + wm + i * 16 + quad * 4;
        float4 bv = make_float4(0.f, 0.f, 0.f, 0.f);
        if (bias) bv = *(const float4*)&bias[(size_t)n * bstride + orow];
#pragma unroll
        for (int j = 0; j < FN; j++) {
            const int bcol = b0 + wn + j * 16 + m16;
            size_t yi = ((size_t)bcol * Nn + n) * (size_t)OO + orow;
            float v0 = acc[i][j][0] + bv.x;
            float v1 = acc[i][j][1] + bv.y;
            float v2 = acc[i][j][2] + bv.z;
            float v3 = acc[i][j][3] + bv.w;
            if (base16) {
                f16x4 bb = *(const f16x4*)&base16[yi];
                v0 += (float)bb[0]; v1 += (float)bb[1];
                v2 += (float)bb[2]; v3 += (float)bb[3];
            }
            f16x4 o4; o4[0] = (f16)v0; o4[1] = (f16)v1; o4[2] = (f16)v2; o4[3] = (f16)v3;
            *(f16x4*)&Y[yi] = o4;
        }
    }
}

// ---------------------------------------------------------------------------
// Weight prep: Wz (24,512,64)=Wx0[:, :64, :]^T; Wt0 (24,512,192)=[Wx0[64:72]|Wh0|0]^T;
// Wt1 (24,512,256)=[Wx1|Wh1]^T
// ---------------------------------------------------------------------------
__global__ __launch_bounds__(256) void prep_w01(
    const float* __restrict__ Wx0, const float* __restrict__ Wh0,
    const float* __restrict__ Wx1, const float* __restrict__ Wh1,
    f16* __restrict__ Wz, f16* __restrict__ Wt0, f16* __restrict__ Wt1)
{
    size_t idx = (size_t)blockIdx.x * 256 + threadIdx.x;
    const size_t nz = (size_t)Nn * 512 * 64;       // 786432
    const size_t n0 = (size_t)Nn * 512 * 192;      // 2359296
    const size_t n1 = (size_t)Nn * 512 * 256;      // 3145728
    if (idx < nz) {
        int k = idx & 63; int o = (idx >> 6) & 511; int n = (int)(idx >> 15);
        Wz[idx] = (f16)Wx0[((size_t)n * 72 + k) * 512 + o];
    } else if (idx < nz + n0) {
        size_t i2 = idx - nz;
        int k = (int)(i2 % 192);
        size_t no = i2 / 192;
        int o = (int)(no & 511); int n = (int)(no >> 9);
        float v = 0.f;
        if (k < 8) v = Wx0[((size_t)n * 72 + 64 + k) * 512 + o];
        else if (k < 136) v = Wh0[((size_t)n * 128 + (k - 8)) * 512 + o];
        Wt0[i2] = (f16)v;
    } else if (idx < nz + n0 + n1) {
        size_t i3 = idx - nz - n0;
        int k = (int)(i3 & 255);
        size_t no = i3 >> 8;
        int o = (int)(no & 511); int n = (int)(no >> 9);
        float v = (k < 128) ? Wx1[((size_t)n * 128 + k) * 512 + o]
                            : Wh1[((size_t)n * 128 + (k - 128)) * 512 + o];
        Wt1[i3] = (f16)v;
    }
}

// Wtf (24,256,128): o<128 -> fcW^T, else fc2W^T
__global__ __launch_bounds__(256) void prep_wf(
    const float* __restrict__ fcW, const float* __restrict__ fc2W,
    f16* __restrict__ Wtf)
{
    size_t idx = (size_t)blockIdx.x * 256 + threadIdx.x;
    if (idx >= (size_t)Nn * 256 * 128) return;
    int k = (int)(idx & 127);
    size_t no = idx >> 7;
    int o = (int)(no & 255); int n = (int)(no >> 8);
    float v = (o < 128) ? fcW[((size_t)n * 128 + k) * 128 + o]
                        : fc2W[((size_t)n * 128 + k) * 128 + (o - 128)];
    Wtf[idx] = (f16)v;
}

// Wti (256,256) = [ih1W | ih2W]^T ; bi (256) ; bcat (24,256)
__global__ __launch_bounds__(256) void prep_wi(
    const float* __restrict__ ih1W, const float* __restrict__ ih2W,
    const float* __restrict__ ih1b, const float* __restrict__ ih2b,
    const float* __restrict__ fcb, const float* __restrict__ fc2b,
    f16* __restrict__ Wti, float* __restrict__ bi, float* __restrict__ bcat)
{
    int idx = blockIdx.x * 256 + threadIdx.x;   // 65536
    int k = idx & 255, o = idx >> 8;
    Wti[idx] = (f16)((o < 128) ? ih1W[(size_t)k * 128 + o] : ih2W[(size_t)k * 128 + (o - 128)]);
    if (idx < 256) bi[idx] = (idx < 128) ? ih1b[idx] : ih2b[idx - 128];
    if (idx < Nn * 256) {
        int n = idx >> 8, oo = idx & 255;
        bcat[idx] = (oo < 128) ? fcb[n * 128 + oo] : fc2b[n * 128 + (oo - 128)];
    }
}

// xi2[b,n,0:8)=x, [136:192)=0 ([8:136) = h1, filled by mix_init/mixlstm); ls=x[:4]
__global__ __launch_bounds__(256) void init_xi(
    const float* __restrict__ x, f16* __restrict__ xi2, float* __restrict__ ls)
{
    size_t idx = (size_t)blockIdx.x * 256 + threadIdx.x;
    const size_t total = (size_t)Bsz * Nn * 192;
    if (idx < total) {
        size_t bn = idx / 192;
        int k = (int)(idx - bn * 192);
        if (k < 8) xi2[idx] = (f16)x[bn * 8 + k];
        else if (k >= 136) xi2[idx] = (f16)0.f;
    }
    if (idx < (size_t)Bsz * Nn * 4) {
        size_t bn = idx >> 2;
        ls[idx] = x[bn * 8 + (idx & 3)];
    }
}

// ---------------------------------------------------------------------------
// Init mix: Yhc (B,N,256) f16 = [h-pre | c-pre]; h0 -> xi2[8:136), l2cat[0:128),
// l2cat[128:256); c0 -> c1, c2 (fp32).
// ---------------------------------------------------------------------------
__global__ __launch_bounds__(256) void mix_init(
    const f16* __restrict__ Yhc, const float* __restrict__ G,
    f16* __restrict__ xi2, f16* __restrict__ l2cat,
    float* __restrict__ c1, float* __restrict__ c2)
{
    const int b = blockIdx.x;
    const int tid = threadIdx.x;
    __shared__ float sY[6144], sG[576];
    for (int i = tid; i < 576; i += 256) sG[i] = G[i];
    for (int v = tid; v < 768; v += 256) {
        int c8 = (v & 31) * 8, n = v >> 5;
        f16x8 t = *(const f16x8*)&Yhc[((size_t)b * Nn + n) * 256 + c8];
        float* d = &sY[n * 256 + c8];
#pragma unroll
        for (int u = 0; u < 8; u++) d[u] = (float)t[u];
    }
    __syncthreads();
    for (int w = tid; w < 3072; w += 256) {
        int o = w & 127, m = w >> 7;
        float ah = 0.f, ac = 0.f;
#pragma unroll
        for (int n = 0; n < 24; n++) {
            float g = sG[m * 24 + n];
            ah += g * sY[n * 256 + o];
            ac += g * sY[n * 256 + 128 + o];
        }
        size_t row = (size_t)b * Nn + m;
        f16 hf = (f16)ah;
        xi2[row * 192 + 8 + o] = hf;
        l2cat[row * 256 + o] = hf;
        l2cat[row * 256 + 128 + o] = hf;
        c1[row * 128 + o] = ac;
        c2[row * 128 + o] = ac;
    }
}

// ---------------------------------------------------------------------------
// G-mix + LSTM pointwise. Ypre (B,N,512) f16 pre-mix gates. c fp32 in/out.
// h written f16 to dstA (raw) and dstB (raw or tanh). grid (B, 2 j-tiles).
// ---------------------------------------------------------------------------
__global__ __launch_bounds__(256) void mixlstm(
    const f16* __restrict__ Ypre, const float* __restrict__ G,
    float* __restrict__ c,
    f16* __restrict__ dstA, int strideA,
    f16* __restrict__ dstB, int strideB, int tanhB)
{
    const int b = blockIdx.x;
    const int jt = blockIdx.y * 64;
    const int tid = threadIdx.x;
    __shared__ float sY[6144];   // n, gate, j(64)
    __shared__ float sG[576];
    for (int i = tid; i < 576; i += 256) sG[i] = G[i];
    for (int v = tid; v < 768; v += 256) {
        int j8 = (v & 7) * 8, g = (v >> 3) & 3, n = v >> 5;
        f16x8 t = *(const f16x8*)&Ypre[((size_t)b * Nn + n) * 512 + g * 128 + jt + j8];
        float* d = &sY[n * 256 + g * 64 + j8];
#pragma unroll
        for (int u = 0; u < 8; u++) d[u] = (float)t[u];
    }
    __syncthreads();
    for (int w = tid; w < 1536; w += 256) {
        int j = w & 63, m = w >> 6;
        float gi = 0.f, gf = 0.f, gg = 0.f, go = 0.f;
        const float* gr = &sG[m * 24];
#pragma unroll
        for (int n = 0; n < 24; n++) {
            float g = gr[n];
            gi += g * sY[n * 256 + j];
            gf += g * sY[n * 256 + 64 + j];
            gg += g * sY[n * 256 + 128 + j];
            go += g * sY[n * 256 + 192 + j];
        }
        int col = jt + j;
        size_t row = (size_t)b * Nn + m;
        float cv = c[row * 128 + col];
        float si = 1.f / (1.f + expf(-gi));
        float sf = 1.f / (1.f + expf(-gf));
        float so = 1.f / (1.f + expf(-go));
        float tg = tanhf(gg);
        cv = sf * cv + si * tg;
        c[row * 128 + col] = cv;
        float h = so * tanhf(cv);
        dstA[row * strideA + col] = (f16)h;
        dstB[row * strideB + col] = (f16)(tanhB ? tanhf(h) : h);
    }
}

// ---------------------------------------------------------------------------
// Final per-step: mix fc pre-acts + tanh, head matvecs, second mix, quat,
// outputs, update xi2[0:8) & loc_start. p (B,N,256) f16 = [fc1-pre | fc2-pre].
// ---------------------------------------------------------------------------
__global__ __launch_bounds__(256) void finstep(
    const f16* __restrict__ p, const float* __restrict__ G,
    const float* __restrict__ locW, const float* __restrict__ locb,
    const float* __restrict__ lzW, const float* __restrict__ lzb,
    float* __restrict__ ls, f16* __restrict__ xi2,
    float* __restrict__ out, int t)
{
    const int b = blockIdx.x;
    const int tid = threadIdx.x;
    __shared__ float sP[6144], sY1[3072], sY2[3072];
    __shared__ float sG[576];
    __shared__ float sLp[24][3], sZp[24][4], sL3[24][3], sZ3[24][4];
    for (int i = tid; i < 576; i += 256) sG[i] = G[i];
    for (int v = tid; v < 768; v += 256) {
        int c8 = (v & 31) * 8, n = v >> 5;
        f16x8 tv = *(const f16x8*)&p[((size_t)b * Nn + n) * 256 + c8];
        float* d = &sP[n * 256 + c8];
#pragma unroll
        for (int u = 0; u < 8; u++) d[u] = (float)tv[u];
    }
    __syncthreads();
    for (int w = tid; w < 3072; w += 256) {
        int o = w & 127, m = w >> 7;
        float a1 = 0.f, a2 = 0.f;
#pragma unroll
        for (int n = 0; n < 24; n++) {
            float g = sG[m * 24 + n];
            a1 += g * sP[n * 256 + o];
            a2 += g * sP[n * 256 + 128 + o];
        }
        sY1[w] = tanhf(a1);
        sY2[w] = tanhf(a2);
    }
    __syncthreads();
    if (tid < 72) {
        int m = tid / 3, j = tid - m * 3;
        float s = locb[j];
        for (int o = 0; o < 128; o++) s += sY1[m * 128 + o] * locW[o * 3 + j];
        sLp[m][j] = s;
    } else if (tid < 168) {
        int w2 = tid - 72; int m = w2 >> 2, j = w2 & 3;
        float s = lzb[j];
        for (int o = 0; o < 128; o++) s += sY2[m * 128 + o] * lzW[o * 4 + j];
        sZp[m][j] = s;
    }
    __syncthreads();
    if (tid < 72) {
        int m = tid / 3, j = tid - m * 3;
        float s = 0.f;
#pragma unroll
        for (int n = 0; n < 24; n++) s += sG[m * 24 + n] * sLp[n][j];
        sL3[m][j] = s;
    } else if (tid < 168) {
        int w2 = tid - 72; int m = w2 >> 2, j = w2 & 3;
        float s = 0.f;
#pragma unroll
        for (int n = 0; n < 24; n++) s += sG[m * 24 + n] * sZp[n][j];
        sZ3[m][j] = s;
    }
    __syncthreads();
    if (tid < 24) {
        int m = tid;
        float xx = sL3[m][0], xy = sL3[m][1], xz = sL3[m][2];
        float r = rsqrtf(1.f + xx * xx + xy * xy + xz * xz);
        float dw = r, dx = xx * r, dy = xy * r, dz = xz * r;
        size_t li = ((size_t)b * Nn + m) * 4;
        float qw = ls[li], qx = ls[li + 1], qy = ls[li + 2], qz = ls[li + 3];
        float lw = qw * dw - qx * dx - qy * dy - qz * dz;
        float lx = qw * dx + qx * dw + qy * dz - qz * dy;
        float ly = qw * dy - qx * dz + qy * dw + qz * dx;
        float lz = qw * dz + qx * dy - qy * dx + qz * dw;
        size_t oi = (((size_t)b * Tt + t) * Nn + m) * 4;
        out[oi + 0] = lw; out[oi + 1] = lx; out[oi + 2] = ly; out[oi + 3] = lz;
        size_t zi = (size_t)Bsz * Tt * Nn * 4 + oi;
        out[zi + 0] = sZ3[m][0]; out[zi + 1] = sZ3[m][1];
        out[zi + 2] = sZ3[m][2]; out[zi + 3] = sZ3[m][3];
        ls[li] = lw; ls[li + 1] = lx; ls[li + 2] = ly; ls[li + 3] = lz;
        size_t xb = ((size_t)b * Nn + m) * 192;
        xi2[xb + 0] = (f16)lw; xi2[xb + 1] = (f16)lx; xi2[xb + 2] = (f16)ly; xi2[xb + 3] = (f16)lz;
        xi2[xb + 4] = (f16)dw; xi2[xb + 5] = (f16)dx; xi2[xb + 6] = (f16)dy; xi2[xb + 7] = (f16)dz;
    }
}

extern "C" void kernel_launch(void* const* d_in, const int* in_sizes, int n_in,
                              void* d_out, int out_size, void* d_ws, size_t ws_size,
                              hipStream_t stream)
{
    const float* x    = (const float*)d_in[0];
    const float* enc  = (const float*)d_in[1];
    const float* z    = (const float*)d_in[2];
    const float* G    = (const float*)d_in[4];
    const float* Wx0  = (const float*)d_in[5];
    const float* Wh0  = (const float*)d_in[6];
    const float* b0i  = (const float*)d_in[7];
    const float* Wx1  = (const float*)d_in[8];
    const float* Wh1  = (const float*)d_in[9];
    const float* b1i  = (const float*)d_in[10];
    const float* fcW  = (const float*)d_in[11];
    const float* fcb  = (const float*)d_in[12];
    const float* fc2W = (const float*)d_in[13];
    const float* fc2b = (const float*)d_in[14];
    const float* ih1W = (const float*)d_in[15];
    const float* ih1b = (const float*)d_in[16];
    const float* ih2W = (const float*)d_in[17];
    const float* ih2b = (const float*)d_in[18];
    const float* locW = (const float*)d_in[19];
    const float* locb = (const float*)d_in[20];
    const float* lzW  = (const float*)d_in[21];
    const float* lzb  = (const float*)d_in[22];
    float* out = (float*)d_out;

    const size_t BN = (size_t)Bsz * Nn;
    char* wp = (char*)d_ws;
    size_t off = 0;
    auto carve = [&](size_t bytes) -> char* {
        char* pc = wp + off;
        off += (bytes + 255) & ~(size_t)255;
        return pc;
    };
    f16*   Wz     = (f16*)carve((size_t)Nn * 512 * 64 * 2);
    f16*   Wt0    = (f16*)carve((size_t)Nn * 512 * 192 * 2);
    f16*   Wt1    = (f16*)carve((size_t)Nn * 512 * 256 * 2);
    f16*   Wtf    = (f16*)carve((size_t)Nn * 256 * 128 * 2);
    f16*   Wti    = (f16*)carve((size_t)256 * 256 * 2);
    float* bcat   = (float*)carve((size_t)Nn * 256 * 4);
    float* bi     = (float*)carve(256 * 4);
    f16*   base1  = (f16*)carve(BN * 512 * 2);
    f16*   xi2    = (f16*)carve(BN * 192 * 2);
    f16*   l2cat  = (f16*)carve(BN * 256 * 2);
    f16*   yib    = (f16*)carve(BN * 128 * 2);
    float* c1     = (float*)carve(BN * 128 * 4);
    float* c2     = (float*)carve(BN * 128 * 4);
    float* ls     = (float*)carve(BN * 4 * 4);
    f16*   yp     = (f16*)carve(BN * 512 * 2);
    f16*   pbuf   = (f16*)carve(BN * 256 * 2);

    // ---- one-time prep ----
    prep_w01<<<24576, 256, 0, stream>>>(Wx0, Wh0, Wx1, Wh1, Wz, Wt0, Wt1);
    prep_wf<<<3072, 256, 0, stream>>>(fcW, fc2W, Wtf);
    prep_wi<<<256, 256, 0, stream>>>(ih1W, ih2W, ih1b, ih2b, fcb, fc2b, Wti, bi, bcat);
    init_xi<<<9216, 256, 0, stream>>>(x, xi2, ls);

    // base1 = z . Wx0[:,:64,:] + b0    (constant over all T steps)
    gemm_mfma<2, 4, 64, 512><<<dim3(8, 4, 24), 256, 0, stream>>>(
        nullptr, z, Wz, (size_t)512 * 64, b0i, 512, nullptr, base1);
    // init states: [h0|c0] from enc
    gemm_mfma<2, 4, 256, 256><<<dim3(4, 4, 24), 256, 0, stream>>>(
        nullptr, enc, Wti, 0, bi, 0, nullptr, yp);
    mix_init<<<512, 256, 0, stream>>>(yp, G, xi2, l2cat, c1, c2);

    // ---- T sequential steps ----
    for (int t = 0; t < Tt; t++) {
        // layer-1 gates: K padded 192, real K = 136 -> last half-tile skipped
        gemm_mfma<2, 4, 192, 512, 136><<<dim3(8, 4, 24), 256, 0, stream>>>(
            xi2, nullptr, Wt0, (size_t)512 * 192, nullptr, 0, base1, yp);
        mixlstm<<<dim3(512, 2), 256, 0, stream>>>(yp, G, c1, xi2 + 8, 192, l2cat, 256, 0);
        gemm_mfma<2, 4, 256, 512><<<dim3(8, 4, 24), 256, 0, stream>>>(
            l2cat, nullptr, Wt1, (size_t)512 * 256, b1i, 512, nullptr, yp);
        mixlstm<<<dim3(512, 2), 256, 0, stream>>>(yp, G, c2, l2cat + 128, 256, yib, 128, 1);
        gemm_mfma<2, 4, 128, 256><<<dim3(4, 4, 24), 256, 0, stream>>>(
            yib, nullptr, Wtf, (size_t)256 * 128, bcat, 256, nullptr, pbuf);
        finstep<<<512, 256, 0, stream>>>(pbuf, G, locW, locb, lzW, lzb, ls, xi2, out, t);
    }
}